// Round 2
// baseline (1003.982 us; speedup 1.0000x reference)
//
#include <hip/hip_runtime.h>

typedef unsigned int uint32;
typedef unsigned short u16;

#define DEVINL static __device__ __forceinline__

DEVINL float bf2f(u16 u){ return __uint_as_float(((uint32)u) << 16); }
DEVINL u16 f2bf(float f){
  uint32 u = __float_as_uint(f);
  u += 0x7fffu + ((u >> 16) & 1u);   // RNE
  return (u16)(u >> 16);
}
DEVINL void unpack2(uint32 u, float &a, float &b){
  a = __uint_as_float(u << 16);
  b = __uint_as_float(u & 0xffff0000u);
}
DEVINL uint32 pack2(float a, float b){
  return (uint32)f2bf(a) | (((uint32)f2bf(b)) << 16);
}
template<int M> DEVINL float loadElem(const void* p, size_t i){
  return M ? bf2f(((const u16*)p)[i]) : ((const float*)p)[i];
}

// ---------------- dtype detector ----------------
// bf16-pair data: low u16 of each u32 is a sane bf16 (~100%).
// fp32 data: low u16 is mantissa bits -> ~20% sane. Threshold 50%.
__global__ void detect_k(const uint32* __restrict__ x, uint32* __restrict__ flag){
  const int lane = threadIdx.x;   // 64 threads
  int sane = 0;
  for (int i = 0; i < 32; ++i){
    uint32 u = x[i * 64 + lane];
    uint32 e = (u >> 7) & 0xffu;       // bf16 exponent of low element
    sane += (e >= 100u && e <= 150u) ? 1 : 0;
  }
  for (int off = 32; off >= 1; off >>= 1) sane += __shfl_xor(sane, off);
  if (lane == 0) *flag = (sane > 1024) ? 1u : 0u;   // 1 = bf16, 0 = fp32
}

// ---------------- all weights -> f32 blob ----------------
template<int M>
__global__ void cvtall_k(const void* s0, const void* s1, const void* s2,
                         const void* s3, const void* s4, const void* s5,
                         const void* s6, const void* s7, const void* s8,
                         float* __restrict__ wb, const uint32* __restrict__ flag)
{
  if (*flag != (uint32)M) return;
  const int i = blockIdx.x * 256 + threadIdx.x;
  if (i >= 196864) return;
  const void* s; int j;
  if      (i < 4096)   { s = s0; j = i; }
  else if (i < 8192)   { s = s1; j = i - 4096; }
  else if (i < 12288)  { s = s2; j = i - 8192; }
  else if (i < 49152)  { s = s3; j = i - 12288; }
  else if (i < 49216)  { s = s4; j = i - 49152; }
  else if (i < 122944) { s = s5; j = i - 49216; }
  else if (i < 123072) { s = s6; j = i - 122944; }
  else if (i < 196800) { s = s7; j = i - 123072; }
  else                 { s = s8; j = i - 196800; }
  wb[i] = M ? bf2f(((const u16*)s)[j]) : ((const float*)s)[j];
}

// ---------------- G = Q @ K^T  (G[c][d] = sum_e Q[c][e] K[d][e]) ----------------
__global__ void gcomp_k(const float* __restrict__ wb, float* __restrict__ G){
  const int t = blockIdx.x * 256 + threadIdx.x;   // 4096 threads
  const int c = t >> 6, d = t & 63;
  const float* __restrict__ Q = wb;
  const float* __restrict__ K = wb + 4096;
  float s = 0.f;
#pragma unroll
  for (int e = 0; e < 64; ++e) s = fmaf(Q[c * 64 + e], K[d * 64 + e], s);
  G[t] = s;
}

// ---------------- fused attention ----------------
// wave = pixel, lane = channel. s_n = x_n . (x G); attn = (sum alpha_n x_n) V.
// OOB neighbor -> score exactly 0 (participates in softmax), faithful to ref.
template<int M>
__global__ __launch_bounds__(256)
void attn_k(const void* __restrict__ xv, const float* __restrict__ Vf,
            const float* __restrict__ G, u16* __restrict__ tb,
            const uint32* __restrict__ flag)
{
  if (*flag != (uint32)M) return;
  const int lane = threadIdx.x & 63;
  const int p = blockIdx.x * 4 + (threadIdx.x >> 6);
  const int wq = p & 127, hq = (p >> 7) & 127;

  const float xl = loadElem<M>(xv, (size_t)p * 64 + lane);

  float r = 0.f;                       // r_l = sum_d x_d * G[d][l]
#pragma unroll
  for (int d = 0; d < 64; ++d)
    r = fmaf(__shfl(xl, d), G[d * 64 + lane], r);

  float xn[9], sc[9];
#pragma unroll
  for (int kk = 0; kk < 9; ++kk){
    const int di = kk / 3 - 1, dj = kk % 3 - 1;
    const int hh = hq + di, ww = wq + dj;
    const bool valid = (hh >= 0) & (hh < 128) & (ww >= 0) & (ww < 128);
    const int np = valid ? (p + di * 128 + dj) : p;
    float v = valid ? loadElem<M>(xv, (size_t)np * 64 + lane) : 0.f;
    xn[kk] = v;
    float s = v * r;
#pragma unroll
    for (int off = 32; off >= 1; off >>= 1) s += __shfl_xor(s, off);
    sc[kk] = s;
  }
  float mx = sc[0];
#pragma unroll
  for (int kk = 1; kk < 9; ++kk) mx = fmaxf(mx, sc[kk]);
  float ex[9], sum = 0.f;
#pragma unroll
  for (int kk = 0; kk < 9; ++kk){ ex[kk] = __expf(sc[kk] - mx); sum += ex[kk]; }
  const float inv = 1.f / sum;
  float y = 0.f;
#pragma unroll
  for (int kk = 0; kk < 9; ++kk) y = fmaf(ex[kk], xn[kk], y);
  y *= inv;

  float at = 0.f;                      // attn_l = sum_c y_c * V[c][l]
#pragma unroll
  for (int c = 0; c < 64; ++c)
    at = fmaf(__shfl(y, c), Vf[c * 64 + lane], at);

  tb[(size_t)p * 64 + lane] = f2bf(xl + at);
}

// ---------------- 3x3 conv (SAME, zero pad) + ReLU (+ optional residual) ----------------
// in: bf16 always. weights/bias: f32 blob. res: bf16 (tb). out: MOUT<0 -> bf16,
// MOUT==0 -> f32 (gated), MOUT==1 -> bf16 (gated).
template<int CIN, int COUT, int NCO, bool RES, int MOUT>
__global__ __launch_bounds__(256)
void conv_k(const u16* __restrict__ in, const float* __restrict__ wf,
            const float* __restrict__ bias, const u16* __restrict__ res,
            void* __restrict__ out, const uint32* __restrict__ flag)
{
  if (MOUT >= 0){ if (*flag != (uint32)MOUT) return; }
  const int p = blockIdx.x * 256 + threadIdx.x;
  const int co0 = blockIdx.y * NCO;
  const int wq = p & 127, hq = (p >> 7) & 127;

  float acc[NCO];
#pragma unroll
  for (int c = 0; c < NCO; ++c) acc[c] = bias[co0 + c];

#pragma unroll 1
  for (int tap = 0; tap < 9; ++tap){
    const int di = tap / 3 - 1, dj = tap % 3 - 1;   // HWIO tap = kh*3+kw
    const int hh = hq + di, ww = wq + dj;
    const bool valid = (hh >= 0) & (hh < 128) & (ww >= 0) & (ww < 128);
    const int np = valid ? (p + di * 128 + dj) : p;
    const uint4* __restrict__ ip = (const uint4*)(in + (size_t)np * CIN);
    const float* __restrict__ wt = wf + tap * (CIN * COUT) + co0;
#pragma unroll 1
    for (int c0 = 0; c0 < CIN / 8; ++c0){
      uint4 u = ip[c0];
      u.x = valid ? u.x : 0u;  u.y = valid ? u.y : 0u;
      u.z = valid ? u.z : 0u;  u.w = valid ? u.w : 0u;
      float xf[8];
      unpack2(u.x, xf[0], xf[1]);  unpack2(u.y, xf[2], xf[3]);
      unpack2(u.z, xf[4], xf[5]);  unpack2(u.w, xf[6], xf[7]);
#pragma unroll
      for (int ci = 0; ci < 8; ++ci){
        const float* __restrict__ wr = wt + (c0 * 8 + ci) * COUT;
#pragma unroll
        for (int c = 0; c < NCO; ++c) acc[c] = fmaf(xf[ci], wr[c], acc[c]);
      }
    }
  }

#pragma unroll
  for (int c = 0; c < NCO; ++c) acc[c] = fmaxf(acc[c], 0.f);

  if (RES){
    const uint4* __restrict__ rp = (const uint4*)(res + (size_t)p * COUT + co0);
#pragma unroll
    for (int g = 0; g < NCO / 8; ++g){
      uint4 u = rp[g];
      float rf[8];
      unpack2(u.x, rf[0], rf[1]);  unpack2(u.y, rf[2], rf[3]);
      unpack2(u.z, rf[4], rf[5]);  unpack2(u.w, rf[6], rf[7]);
#pragma unroll
      for (int j = 0; j < 8; ++j) acc[g * 8 + j] += rf[j];
    }
  }

  if (MOUT == 0){
    float* op = (float*)out + (size_t)p * COUT + co0;
#pragma unroll
    for (int c = 0; c < NCO; c += 4){
      float4 o = make_float4(acc[c], acc[c + 1], acc[c + 2], acc[c + 3]);
      *reinterpret_cast<float4*>(op + c) = o;
    }
  } else {
    uint4* op = (uint4*)((u16*)out + (size_t)p * COUT + co0);
#pragma unroll
    for (int g = 0; g < NCO / 8; ++g){
      uint4 o;
      o.x = pack2(acc[g*8+0], acc[g*8+1]);
      o.y = pack2(acc[g*8+2], acc[g*8+3]);
      o.z = pack2(acc[g*8+4], acc[g*8+5]);
      o.w = pack2(acc[g*8+6], acc[g*8+7]);
      op[g] = o;
    }
  }
}

extern "C" void kernel_launch(void* const* d_in, const int* in_sizes, int n_in,
                              void* d_out, int out_size, void* d_ws, size_t ws_size,
                              hipStream_t stream)
{
  (void)in_sizes; (void)n_in; (void)out_size; (void)ws_size;

  // ws layout (65 MiB total)
  char* ws = (char*)d_ws;
  float* wblob = (float*)ws;                         // 196864 f32
  float* G     = wblob + 196864;                     // 4096 f32
  uint32* flag = (uint32*)(ws + (1 << 20) - 16);
  const size_t MB = (size_t)1 << 20;
  u16* tb = (u16*)(ws + 1 * MB);                     // [131072][64]  bf16
  u16* c1 = (u16*)(ws + 17 * MB);                    // [131072][64]  bf16
  u16* c2 = (u16*)(ws + 33 * MB);                    // [131072][128] bf16

  // f32 weight blob offsets
  const int OW1 = 12288, OB1 = 49152, OW2 = 49216, OB2 = 122944,
            OW3 = 123072, OB3 = 196800;

  detect_k<<<1, 64, 0, stream>>>((const uint32*)d_in[0], flag);

  cvtall_k<0><<<769, 256, 0, stream>>>(d_in[1], d_in[2], d_in[3], d_in[4], d_in[5],
                                       d_in[6], d_in[7], d_in[8], d_in[9], wblob, flag);
  cvtall_k<1><<<769, 256, 0, stream>>>(d_in[1], d_in[2], d_in[3], d_in[4], d_in[5],
                                       d_in[6], d_in[7], d_in[8], d_in[9], wblob, flag);

  gcomp_k<<<16, 256, 0, stream>>>(wblob, G);

  attn_k<0><<<32768, 256, 0, stream>>>(d_in[0], wblob + 8192, G, tb, flag);
  attn_k<1><<<32768, 256, 0, stream>>>(d_in[0], wblob + 8192, G, tb, flag);

  conv_k<64, 64, 32, false, -1><<<dim3(512, 2), 256, 0, stream>>>(
      tb, wblob + OW1, wblob + OB1, nullptr, c1, flag);
  conv_k<64, 128, 64, false, -1><<<dim3(512, 2), 256, 0, stream>>>(
      c1, wblob + OW2, wblob + OB2, nullptr, c2, flag);
  conv_k<128, 64, 32, true, 0><<<dim3(512, 2), 256, 0, stream>>>(
      c2, wblob + OW3, wblob + OB3, tb, d_out, flag);
  conv_k<128, 64, 32, true, 1><<<dim3(512, 2), 256, 0, stream>>>(
      c2, wblob + OW3, wblob + OB3, tb, d_out, flag);
}

// Round 4
// 356.337 us; speedup vs baseline: 2.8175x; 2.8175x over previous
//
#include <hip/hip_runtime.h>

typedef unsigned int uint32;
typedef unsigned short u16;
typedef short s16x8 __attribute__((ext_vector_type(8)));
typedef float f32x4 __attribute__((ext_vector_type(4)));

#define DEVINL static __device__ __forceinline__
#define MFMA16(a, b, c) __builtin_amdgcn_mfma_f32_16x16x32_bf16(a, b, c, 0, 0, 0)

DEVINL float bf2f(u16 u){ return __uint_as_float(((uint32)u) << 16); }
DEVINL u16 f2bf(float f){
  uint32 u = __float_as_uint(f);
  u += 0x7fffu + ((u >> 16) & 1u);   // RNE
  return (u16)(u >> 16);
}
DEVINL uint32 pack2(float a, float b){
  return (uint32)f2bf(a) | (((uint32)f2bf(b)) << 16);
}

// ---------------- dtype detector (proven round 2) ----------------
__global__ void detect_k(const uint32* __restrict__ x, uint32* __restrict__ flag){
  const int lane = threadIdx.x;   // 64 threads
  int sane = 0;
  for (int i = 0; i < 32; ++i){
    uint32 u = x[i * 64 + lane];
    uint32 e = (u >> 7) & 0xffu;
    sane += (e >= 100u && e <= 150u) ? 1 : 0;
  }
  for (int off = 32; off >= 1; off >>= 1) sane += __shfl_xor(sane, off);
  if (lane == 0) *flag = (sane > 1024) ? 1u : 0u;   // 1 = bf16, 0 = fp32
}

// ---------------- all weights -> f32 blob (proven round 2) ----------------
template<int M>
__global__ void cvtall_k(const void* s0, const void* s1, const void* s2,
                         const void* s3, const void* s4, const void* s5,
                         const void* s6, const void* s7, const void* s8,
                         float* __restrict__ wb, const uint32* __restrict__ flag)
{
  if (*flag != (uint32)M) return;
  const int i = blockIdx.x * 256 + threadIdx.x;
  if (i >= 196864) return;
  const void* s; int j;
  if      (i < 4096)   { s = s0; j = i; }
  else if (i < 8192)   { s = s1; j = i - 4096; }
  else if (i < 12288)  { s = s2; j = i - 8192; }
  else if (i < 49152)  { s = s3; j = i - 12288; }
  else if (i < 49216)  { s = s4; j = i - 49152; }
  else if (i < 122944) { s = s5; j = i - 49216; }
  else if (i < 123072) { s = s6; j = i - 122944; }
  else if (i < 196800) { s = s7; j = i - 123072; }
  else                 { s = s8; j = i - 196800; }
  wb[i] = M ? bf2f(((const u16*)s)[j]) : ((const float*)s)[j];
}

// ---------------- x -> bf16 copy/convert ----------------
template<int M>
__global__ __launch_bounds__(256)
void xcvt_k(const void* __restrict__ x, u16* __restrict__ xb,
            const uint32* __restrict__ flag)
{
  if (*flag != (uint32)M) return;
  const size_t i0 = ((size_t)blockIdx.x * 256 + threadIdx.x) * 8;
  if (M){
    *(uint4*)(xb + i0) = *(const uint4*)((const u16*)x + i0);
  } else {
    const float4 f0 = ((const float4*)x)[i0 / 4];
    const float4 f1 = ((const float4*)x)[i0 / 4 + 1];
    uint4 o;
    o.x = pack2(f0.x, f0.y); o.y = pack2(f0.z, f0.w);
    o.z = pack2(f1.x, f1.y); o.w = pack2(f1.z, f1.w);
    *(uint4*)(xb + i0) = o;
  }
}

// ---------------- G = K_P @ Q_P^T -> hi/lo bf16 split ----------------
// gt[d][c] (hi) at bb[0..4096), glo at bb[4096..8192)
__global__ void gcomp_k(const float* __restrict__ wb, u16* __restrict__ gt){
  const int t = blockIdx.x * 256 + threadIdx.x;   // 4096
  const int d = t >> 6, c = t & 63;
  const float* __restrict__ K = wb + 4096;
  const float* __restrict__ Q = wb;
  float s = 0.f;
#pragma unroll
  for (int e = 0; e < 64; ++e) s = fmaf(K[d * 64 + e], Q[c * 64 + e], s);
  const u16 hi = f2bf(s);
  gt[t] = hi;
  gt[4096 + t] = f2bf(s - bf2f(hi));
}

// ---------------- pack vt / w1t / w2t / w3t (bf16) ----------------
__global__ void pack_k(const float* __restrict__ wb, u16* __restrict__ bb){
  int i = blockIdx.x * 256 + threadIdx.x;   // grid exact: 188416
  if (i < 4096){                                      // vt[o][c] = V[c][o]
    const int o = i >> 6, c = i & 63;
    bb[8192 + i] = f2bf(wb[8192 + c * 64 + o]);
    return;
  }
  i -= 4096;
  if (i < 36864){                                     // w1t[tap][co][ci]
    const int tap = i >> 12, co = (i >> 6) & 63, ci = i & 63;
    bb[12288 + i] = f2bf(wb[12288 + (tap * 64 + ci) * 64 + co]);
    return;
  }
  i -= 36864;
  if (i < 73728){                                     // w2t[tap][co(128)][ci(64)]
    const int tap = i >> 13, co = (i >> 6) & 127, ci = i & 63;
    bb[49152 + i] = f2bf(wb[49216 + (tap * 64 + ci) * 128 + co]);
    return;
  }
  i -= 73728;
  {                                                   // w3t[tap][co(64)][ci(128)]
    const int tap = i >> 13, co = (i >> 7) & 63, ci = i & 127;
    bb[122880 + i] = f2bf(wb[123072 + (tap * 128 + ci) * 64 + co]);
  }
}

// ---------------- halo staging into swizzled LDS ----------------
// element ci of (row,col) lives at (row*(BPX+2)+col)*CIN + ((ci>>3)^(col&7))*8 + (ci&7)
template<int BPX, int CIN>
DEVINL void stage_tile(const u16* __restrict__ img_base, int h, int w0, u16* lds){
  const int CH8 = CIN / 8;
  const int NCH = 3 * (BPX + 2) * CH8;
  for (int idx = threadIdx.x; idx < NCH; idx += 256){
    const int row  = idx / ((BPX + 2) * CH8);
    const int rem  = idx - row * (BPX + 2) * CH8;
    const int col  = rem / CH8;
    const int slot = rem - col * CH8;
    const int hi = h + row - 1, wi = w0 + col - 1;
    uint4 v = make_uint4(0u, 0u, 0u, 0u);
    if (hi >= 0 && hi < 128 && wi >= 0 && wi < 128)
      v = *(const uint4*)(img_base + (size_t)(hi * 128 + wi) * CIN + slot * 8);
    const int dst = (row * (BPX + 2) + col) * CIN + ((slot ^ (col & 7)) << 3);
    *(uint4*)(lds + dst) = v;
  }
}

// ---------------- fused 3x3 pixel attention (MFMA, hi/lo G and y) ----------------
__global__ __launch_bounds__(256)
void attn_mfma(const u16* __restrict__ xb, const u16* __restrict__ gt,
               const u16* __restrict__ vt, u16* __restrict__ tb)
{
  __shared__ u16 xh[3 * 66 * 64];
  __shared__ u16 yl[64 * 64];
  __shared__ u16 yl2[64 * 64];
  const int bx = blockIdx.x;
  const int img = bx >> 8, h = (bx >> 1) & 127, w0 = (bx & 1) * 64;
  const int p0 = img * 16384 + h * 128 + w0;
  stage_tile<64, 64>(xb + (size_t)img * 16384 * 64, h, w0, xh);
  __syncthreads();

  const int lane = threadIdx.x & 63, wv = threadIdx.x >> 6;
  const int l15 = lane & 15, lk = lane >> 4;

  // r[p][d] = sum_c x[p][c] G[d][c], G = Ghi + Glo
  f32x4 racc[4];
#pragma unroll
  for (int nt = 0; nt < 4; ++nt) racc[nt] = (f32x4){0.f, 0.f, 0.f, 0.f};
#pragma unroll
  for (int half = 0; half < 2; ++half){
#pragma unroll
    for (int ks = 0; ks < 2; ++ks){
      const int pxl = wv * 16 + l15;
      const int col = pxl + 1;
      const int slot = ks * 4 + lk;
      const s16x8 af = *(const s16x8*)&xh[(66 + col) * 64 + ((slot ^ (col & 7)) << 3)];
#pragma unroll
      for (int nt = 0; nt < 4; ++nt){
        const s16x8 bf = *(const s16x8*)(gt + half * 4096 +
                          (size_t)(nt * 16 + l15) * 64 + ks * 32 + lk * 8);
        racc[nt] = MFMA16(af, bf, racc[nt]);
      }
    }
  }
  // lane holds r[px = wv*16+lk*4+reg][d = nt*16+l15]

  float alpha[4][9];
#pragma unroll
  for (int reg = 0; reg < 4; ++reg){
    const int pxm = wv * 16 + lk * 4 + reg;
#pragma unroll
    for (int n = 0; n < 9; ++n){
      const int tr = n / 3, tc = n % 3;
      const int col = pxm + tc;
      float s = 0.f;
#pragma unroll
      for (int nt = 0; nt < 4; ++nt){
        const int e = nt * 16 + l15;
        const int elem = (tr * 66 + col) * 64 + (((e >> 3) ^ (col & 7)) << 3) + (e & 7);
        s = fmaf(bf2f(xh[elem]), racc[nt][reg], s);
      }
      s += __shfl_xor(s, 1); s += __shfl_xor(s, 2);
      s += __shfl_xor(s, 4); s += __shfl_xor(s, 8);
      alpha[reg][n] = s;
    }
    float mx = alpha[reg][0];
#pragma unroll
    for (int n = 1; n < 9; ++n) mx = fmaxf(mx, alpha[reg][n]);
    float sum = 0.f;
#pragma unroll
    for (int n = 0; n < 9; ++n){
      const float e = __expf(alpha[reg][n] - mx);
      alpha[reg][n] = e; sum += e;
    }
    const float inv = 1.f / sum;
#pragma unroll
    for (int n = 0; n < 9; ++n) alpha[reg][n] *= inv;
  }

  // y[p][e] = sum_n alpha x_n[e]  -> hi/lo bf16 pair in LDS
#pragma unroll
  for (int reg = 0; reg < 4; ++reg){
    const int pxm = wv * 16 + lk * 4 + reg;
#pragma unroll
    for (int nt = 0; nt < 4; ++nt){
      const int e = nt * 16 + l15;
      float y = 0.f;
#pragma unroll
      for (int n = 0; n < 9; ++n){
        const int tr = n / 3, tc = n % 3;
        const int col = pxm + tc;
        const int elem = (tr * 66 + col) * 64 + (((e >> 3) ^ (col & 7)) << 3) + (e & 7);
        y = fmaf(alpha[reg][n], bf2f(xh[elem]), y);
      }
      const u16 hi = f2bf(y);
      const int idx = pxm * 64 + (((e >> 3) ^ (pxm & 7)) << 3) + (e & 7);
      yl[idx]  = hi;
      yl2[idx] = f2bf(y - bf2f(hi));
    }
  }
  __syncthreads();

  // t = x + (yhi + ylo) @ V   (B^T rows vt[o][c])
  f32x4 tacc[4];
#pragma unroll
  for (int nt = 0; nt < 4; ++nt) tacc[nt] = (f32x4){0.f, 0.f, 0.f, 0.f};
#pragma unroll
  for (int half = 0; half < 2; ++half){
    const u16* yb = half ? yl2 : yl;
#pragma unroll
    for (int ks = 0; ks < 2; ++ks){
      const int px = wv * 16 + l15;
      const int slot = ks * 4 + lk;
      const s16x8 af = *(const s16x8*)&yb[px * 64 + ((slot ^ (px & 7)) << 3)];
#pragma unroll
      for (int nt = 0; nt < 4; ++nt){
        const s16x8 bf = *(const s16x8*)(vt + (size_t)(nt * 16 + l15) * 64 + ks * 32 + lk * 8);
        tacc[nt] = MFMA16(af, bf, tacc[nt]);
      }
    }
  }
#pragma unroll
  for (int nt = 0; nt < 4; ++nt){
#pragma unroll
    for (int reg = 0; reg < 4; ++reg){
      const int pxm = wv * 16 + lk * 4 + reg;
      const int co = nt * 16 + l15;
      const int col = pxm + 1;
      const int elem = (66 + col) * 64 + (((co >> 3) ^ (col & 7)) << 3) + (co & 7);
      tb[(size_t)(p0 + pxm) * 64 + co] = f2bf(bf2f(xh[elem]) + tacc[nt][reg]);
    }
  }
}

// ---------------- 3x3 conv via MFMA implicit GEMM ----------------
template<int CIN, int COUT_FULL, int ATILES, bool RES, int MOUT>
__global__ __launch_bounds__(256)
void conv_mfma(const u16* __restrict__ in, const u16* __restrict__ wt,
               const float* __restrict__ bias, const u16* __restrict__ res,
               void* __restrict__ out, const uint32* __restrict__ flag)
{
  if (MOUT >= 0){ if (*flag != (uint32)MOUT) return; }
  constexpr int BPX = 64 * ATILES;
  constexpr int KS  = CIN / 32;
  constexpr int TOT = 9 * KS;
  constexpr int LW  = BPX + 2;
  __shared__ u16 xh[3 * LW * CIN];

  constexpr int RB = 128 / BPX;
  const int bx  = blockIdx.x;
  const int img = bx / (128 * RB);
  const int rem = bx - img * 128 * RB;
  const int h   = rem / RB;
  const int w0  = (rem - h * RB) * BPX;
  const int p0  = img * 16384 + h * 128 + w0;
  const int co0 = blockIdx.y * 64;

  stage_tile<BPX, CIN>(in + (size_t)img * 16384 * CIN, h, w0, xh);
  __syncthreads();

  const int lane = threadIdx.x & 63, wv = threadIdx.x >> 6;
  const int l15 = lane & 15, lk = lane >> 4;

  f32x4 acc[ATILES][4];
#pragma unroll
  for (int nt = 0; nt < 4; ++nt){
    const float b = bias[co0 + nt * 16 + l15];
#pragma unroll
    for (int at = 0; at < ATILES; ++at) acc[at][nt] = (f32x4){b, b, b, b};
  }

  s16x8 b0[4], b1[4];
  auto loadB = [&](int it, s16x8* bb){
    const int tap = it / KS, ks = it - tap * KS;
    const u16* base = wt + (size_t)(tap * COUT_FULL + co0 + l15) * CIN + ks * 32 + lk * 8;
#pragma unroll
    for (int nt = 0; nt < 4; ++nt) bb[nt] = *(const s16x8*)(base + (size_t)nt * 16 * CIN);
  };
  auto doM = [&](int it, s16x8* bb){
    const int tap = it / KS, ks = it - tap * KS;
    const int tr = tap / 3, tc = tap - tr * 3;
    const int slot = ks * 4 + lk;
#pragma unroll
    for (int at = 0; at < ATILES; ++at){
      const int pxl = (wv * ATILES + at) * 16 + l15;
      const int col = pxl + tc;
      const s16x8 af = *(const s16x8*)&xh[(tr * LW + col) * CIN + ((slot ^ (col & 7)) << 3)];
#pragma unroll
      for (int nt = 0; nt < 4; ++nt) acc[at][nt] = MFMA16(af, bb[nt], acc[at][nt]);
    }
  };

  loadB(0, b0);
#pragma unroll 1
  for (int it = 0; it < TOT; it += 2){
    loadB(it + 1, b1);
    doM(it, b0);
    if (it + 2 < TOT) loadB(it + 2, b0);
    doM(it + 1, b1);
  }

#pragma unroll
  for (int at = 0; at < ATILES; ++at){
#pragma unroll
    for (int nt = 0; nt < 4; ++nt){
#pragma unroll
      for (int reg = 0; reg < 4; ++reg){
        float v = fmaxf(acc[at][nt][reg], 0.f);
        const int pxg = p0 + (wv * ATILES + at) * 16 + lk * 4 + reg;
        const int co  = co0 + nt * 16 + l15;
        const size_t oi = (size_t)pxg * COUT_FULL + co;
        if (RES) v += bf2f(res[oi]);
        if (MOUT == 0) ((float*)out)[oi] = v;
        else           ((u16*)out)[oi]   = f2bf(v);
      }
    }
  }
}

extern "C" void kernel_launch(void* const* d_in, const int* in_sizes, int n_in,
                              void* d_out, int out_size, void* d_ws, size_t ws_size,
                              hipStream_t stream)
{
  (void)in_sizes; (void)n_in; (void)out_size; (void)ws_size;

  char* ws = (char*)d_ws;
  float*  wblob = (float*)ws;                            // 196864 f32
  uint32* flag  = (uint32*)(ws + 983040);
  u16*    bb    = (u16*)(ws + (1u << 20));               // bf16 blob (196608)
  u16*    gt  = bb;                                      // [2][64][64] hi/lo
  u16*    vt  = bb + 8192;                               // [64][64]
  u16*    w1t = bb + 12288;                              // [9][64][64]
  u16*    w2t = bb + 49152;                              // [9][128][64]
  u16*    w3t = bb + 122880;                             // [9][64][128]

  u16* xb = (u16*)(ws + (size_t)2097152);                // 16.78 MB (bf16 x)
  u16* c2 = xb;                                          // reuses xb + tail (33.55 MB)
  u16* tb = (u16*)(ws + (size_t)35651584);               // 16.78 MB
  u16* c1 = (u16*)(ws + (size_t)52428800);               // 16.78 MB (ends 69.2 MB)

  detect_k<<<1, 64, 0, stream>>>((const uint32*)d_in[0], flag);

  cvtall_k<0><<<769, 256, 0, stream>>>(d_in[1], d_in[2], d_in[3], d_in[4], d_in[5],
                                       d_in[6], d_in[7], d_in[8], d_in[9], wblob, flag);
  cvtall_k<1><<<769, 256, 0, stream>>>(d_in[1], d_in[2], d_in[3], d_in[4], d_in[5],
                                       d_in[6], d_in[7], d_in[8], d_in[9], wblob, flag);

  xcvt_k<0><<<4096, 256, 0, stream>>>(d_in[0], xb, flag);
  xcvt_k<1><<<4096, 256, 0, stream>>>(d_in[0], xb, flag);

  gcomp_k<<<16, 256, 0, stream>>>(wblob, gt);
  pack_k<<<736, 256, 0, stream>>>(wblob, bb);

  attn_mfma<<<2048, 256, 0, stream>>>(xb, gt, vt, tb);

  conv_mfma<64, 64, 2, false, -1><<<dim3(1024, 1), 256, 0, stream>>>(
      tb, w1t, wblob + 49152, nullptr, c1, flag);
  conv_mfma<64, 128, 2, false, -1><<<dim3(1024, 2), 256, 0, stream>>>(
      c1, w2t, wblob + 122944, nullptr, c2, flag);
  conv_mfma<128, 64, 1, true, 0><<<dim3(2048, 1), 256, 0, stream>>>(
      c2, w3t, wblob + 196800, tb, d_out, flag);
  conv_mfma<128, 64, 1, true, 1><<<dim3(2048, 1), 256, 0, stream>>>(
      c2, w3t, wblob + 196800, tb, d_out, flag);
}

// Round 5
// 212.711 us; speedup vs baseline: 4.7199x; 1.6752x over previous
//
#include <hip/hip_runtime.h>

typedef unsigned int uint32;
typedef unsigned short u16;
typedef short s16x8 __attribute__((ext_vector_type(8)));
typedef float f32x4 __attribute__((ext_vector_type(4)));

#define DEVINL static __device__ __forceinline__
#define MFMA16(a, b, c) __builtin_amdgcn_mfma_f32_16x16x32_bf16(a, b, c, 0, 0, 0)

DEVINL float bf2f(u16 u){ return __uint_as_float(((uint32)u) << 16); }
DEVINL u16 f2bf(float f){
  uint32 u = __float_as_uint(f);
  u += 0x7fffu + ((u >> 16) & 1u);   // RNE
  return (u16)(u >> 16);
}
DEVINL uint32 pack2(float a, float b){
  return (uint32)f2bf(a) | (((uint32)f2bf(b)) << 16);
}

// ---------------- dtype detector (proven) ----------------
__global__ void detect_k(const uint32* __restrict__ x, uint32* __restrict__ flag){
  const int lane = threadIdx.x;   // 64 threads
  int sane = 0;
  for (int i = 0; i < 32; ++i){
    uint32 u = x[i * 64 + lane];
    uint32 e = (u >> 7) & 0xffu;
    sane += (e >= 100u && e <= 150u) ? 1 : 0;
  }
  for (int off = 32; off >= 1; off >>= 1) sane += __shfl_xor(sane, off);
  if (lane == 0) *flag = (sane > 1024) ? 1u : 0u;   // 1 = bf16, 0 = fp32
}

// ---------------- all weights -> f32 blob (proven) ----------------
template<int M>
__global__ void cvtall_k(const void* s0, const void* s1, const void* s2,
                         const void* s3, const void* s4, const void* s5,
                         const void* s6, const void* s7, const void* s8,
                         float* __restrict__ wb, const uint32* __restrict__ flag)
{
  if (*flag != (uint32)M) return;
  const int i = blockIdx.x * 256 + threadIdx.x;
  if (i >= 196864) return;
  const void* s; int j;
  if      (i < 4096)   { s = s0; j = i; }
  else if (i < 8192)   { s = s1; j = i - 4096; }
  else if (i < 12288)  { s = s2; j = i - 8192; }
  else if (i < 49152)  { s = s3; j = i - 12288; }
  else if (i < 49216)  { s = s4; j = i - 49152; }
  else if (i < 122944) { s = s5; j = i - 49216; }
  else if (i < 123072) { s = s6; j = i - 122944; }
  else if (i < 196800) { s = s7; j = i - 123072; }
  else                 { s = s8; j = i - 196800; }
  wb[i] = M ? bf2f(((const u16*)s)[j]) : ((const float*)s)[j];
}

// ---------------- x -> bf16 copy/convert ----------------
template<int M>
__global__ __launch_bounds__(256)
void xcvt_k(const void* __restrict__ x, u16* __restrict__ xb,
            const uint32* __restrict__ flag)
{
  if (*flag != (uint32)M) return;
  const size_t i0 = ((size_t)blockIdx.x * 256 + threadIdx.x) * 8;
  if (M){
    *(uint4*)(xb + i0) = *(const uint4*)((const u16*)x + i0);
  } else {
    const float4 f0 = ((const float4*)x)[i0 / 4];
    const float4 f1 = ((const float4*)x)[i0 / 4 + 1];
    uint4 o;
    o.x = pack2(f0.x, f0.y); o.y = pack2(f0.z, f0.w);
    o.z = pack2(f1.x, f1.y); o.w = pack2(f1.z, f1.w);
    *(uint4*)(xb + i0) = o;
  }
}

// ---------------- G = K_P @ Q_P^T -> hi/lo bf16 split ----------------
__global__ void gcomp_k(const float* __restrict__ wb, u16* __restrict__ gt){
  const int t = blockIdx.x * 256 + threadIdx.x;   // 4096
  const int d = t >> 6, c = t & 63;
  const float* __restrict__ K = wb + 4096;
  const float* __restrict__ Q = wb;
  float s = 0.f;
#pragma unroll
  for (int e = 0; e < 64; ++e) s = fmaf(K[d * 64 + e], Q[c * 64 + e], s);
  const u16 hi = f2bf(s);
  gt[t] = hi;
  gt[4096 + t] = f2bf(s - bf2f(hi));
}

// ---------------- pack vt + K-chunked, bank-swizzled conv weights ----------------
// wNpk layout: [chunk][co(64)][kk'(32)], chunk = tap*KS+ks, 4KB each;
// stored kk' has slot' = slot ^ ((co>>1)&3)  (slot = kk>>3).
__global__ void pack_k(const float* __restrict__ wb, u16* __restrict__ bb){
  int i = blockIdx.x * 256 + threadIdx.x;   // grid exact: 188416
  if (i < 4096){                                      // vt[o][c] = V[c][o]
    const int o = i >> 6, c = i & 63;
    bb[8192 + i] = f2bf(wb[8192 + c * 64 + o]);
    return;
  }
  i -= 4096;
  if (i < 36864){                                     // w1pk (18 chunks)
    const int chunk = i >> 11, rr = i & 2047, co = rr >> 5, kkp = rr & 31;
    const int slot = (kkp >> 3) ^ ((co >> 1) & 3), kk = slot * 8 + (kkp & 7);
    const int tap = chunk >> 1, ci = (chunk & 1) * 32 + kk;
    bb[12288 + i] = f2bf(wb[12288 + (tap * 64 + ci) * 64 + co]);
    return;
  }
  i -= 36864;
  if (i < 73728){                                     // w2pk [2 halves][18 chunks]
    const int half = i / 36864, i2 = i - half * 36864;
    const int chunk = i2 >> 11, rr = i2 & 2047, co = rr >> 5, kkp = rr & 31;
    const int slot = (kkp >> 3) ^ ((co >> 1) & 3), kk = slot * 8 + (kkp & 7);
    const int tap = chunk >> 1, ci = (chunk & 1) * 32 + kk;
    bb[49152 + i] = f2bf(wb[49216 + (tap * 64 + ci) * 128 + half * 64 + co]);
    return;
  }
  i -= 73728;
  {                                                   // w3pk (36 chunks)
    const int chunk = i >> 11, rr = i & 2047, co = rr >> 5, kkp = rr & 31;
    const int slot = (kkp >> 3) ^ ((co >> 1) & 3), kk = slot * 8 + (kkp & 7);
    const int tap = chunk >> 2, ci = (chunk & 3) * 32 + kk;
    bb[122880 + i] = f2bf(wb[123072 + (tap * 128 + ci) * 64 + co]);
  }
}

// ---------------- halo staging into swizzled LDS ----------------
// element ci of (row,col) lives at (row*66+col)*CIN + ((ci>>3)^(col&7))*8 + (ci&7)
template<int ROWS, int CIN>
DEVINL void stage_tile(const u16* __restrict__ img_base, int h0, int w0, u16* lds){
  constexpr int CH8 = CIN / 8;
  constexpr int NCH = ROWS * 66 * CH8;
  for (int idx = threadIdx.x; idx < NCH; idx += 256){
    const int row  = idx / (66 * CH8);
    const int rem  = idx - row * 66 * CH8;
    const int col  = rem / CH8;
    const int slot = rem - col * CH8;
    const int hi = h0 + row - 1, wi = w0 + col - 1;
    uint4 v = make_uint4(0u, 0u, 0u, 0u);
    if (hi >= 0 && hi < 128 && wi >= 0 && wi < 128)
      v = *(const uint4*)(img_base + (size_t)(hi * 128 + wi) * CIN + slot * 8);
    const int dst = (row * 66 + col) * CIN + ((slot ^ (col & 7)) << 3);
    *(uint4*)(lds + dst) = v;
  }
}

// ---------------- fused 3x3 pixel attention (MFMA, hi/lo G and y) — proven ----------------
__global__ __launch_bounds__(256)
void attn_mfma(const u16* __restrict__ xb, const u16* __restrict__ gt,
               const u16* __restrict__ vt, u16* __restrict__ tb)
{
  __shared__ __align__(16) u16 xh[3 * 66 * 64];
  __shared__ __align__(16) u16 yl[64 * 64];
  __shared__ __align__(16) u16 yl2[64 * 64];
  const int bx = blockIdx.x;
  const int img = bx >> 8, h = (bx >> 1) & 127, w0 = (bx & 1) * 64;
  const int p0 = img * 16384 + h * 128 + w0;
  stage_tile<3, 64>(xb + (size_t)img * 16384 * 64, h, w0, xh);
  __syncthreads();

  const int lane = threadIdx.x & 63, wv = threadIdx.x >> 6;
  const int l15 = lane & 15, lk = lane >> 4;

  f32x4 racc[4];
#pragma unroll
  for (int nt = 0; nt < 4; ++nt) racc[nt] = (f32x4){0.f, 0.f, 0.f, 0.f};
#pragma unroll
  for (int half = 0; half < 2; ++half){
#pragma unroll
    for (int ks = 0; ks < 2; ++ks){
      const int pxl = wv * 16 + l15;
      const int col = pxl + 1;
      const int slot = ks * 4 + lk;
      const s16x8 af = *(const s16x8*)&xh[(66 + col) * 64 + ((slot ^ (col & 7)) << 3)];
#pragma unroll
      for (int nt = 0; nt < 4; ++nt){
        const s16x8 bf = *(const s16x8*)(gt + half * 4096 +
                          (size_t)(nt * 16 + l15) * 64 + ks * 32 + lk * 8);
        racc[nt] = MFMA16(af, bf, racc[nt]);
      }
    }
  }

  float alpha[4][9];
#pragma unroll
  for (int reg = 0; reg < 4; ++reg){
    const int pxm = wv * 16 + lk * 4 + reg;
#pragma unroll
    for (int n = 0; n < 9; ++n){
      const int tr = n / 3, tc = n % 3;
      const int col = pxm + tc;
      float s = 0.f;
#pragma unroll
      for (int nt = 0; nt < 4; ++nt){
        const int e = nt * 16 + l15;
        const int elem = (tr * 66 + col) * 64 + (((e >> 3) ^ (col & 7)) << 3) + (e & 7);
        s = fmaf(bf2f(xh[elem]), racc[nt][reg], s);
      }
      s += __shfl_xor(s, 1); s += __shfl_xor(s, 2);
      s += __shfl_xor(s, 4); s += __shfl_xor(s, 8);
      alpha[reg][n] = s;
    }
    float mx = alpha[reg][0];
#pragma unroll
    for (int n = 1; n < 9; ++n) mx = fmaxf(mx, alpha[reg][n]);
    float sum = 0.f;
#pragma unroll
    for (int n = 0; n < 9; ++n){
      const float e = __expf(alpha[reg][n] - mx);
      alpha[reg][n] = e; sum += e;
    }
    const float inv = 1.f / sum;
#pragma unroll
    for (int n = 0; n < 9; ++n) alpha[reg][n] *= inv;
  }

#pragma unroll
  for (int reg = 0; reg < 4; ++reg){
    const int pxm = wv * 16 + lk * 4 + reg;
#pragma unroll
    for (int nt = 0; nt < 4; ++nt){
      const int e = nt * 16 + l15;
      float y = 0.f;
#pragma unroll
      for (int n = 0; n < 9; ++n){
        const int tr = n / 3, tc = n % 3;
        const int col = pxm + tc;
        const int elem = (tr * 66 + col) * 64 + (((e >> 3) ^ (col & 7)) << 3) + (e & 7);
        y = fmaf(alpha[reg][n], bf2f(xh[elem]), y);
      }
      const u16 hi = f2bf(y);
      const int idx = pxm * 64 + (((e >> 3) ^ (pxm & 7)) << 3) + (e & 7);
      yl[idx]  = hi;
      yl2[idx] = f2bf(y - bf2f(hi));
    }
  }
  __syncthreads();

  f32x4 tacc[4];
#pragma unroll
  for (int nt = 0; nt < 4; ++nt) tacc[nt] = (f32x4){0.f, 0.f, 0.f, 0.f};
#pragma unroll
  for (int half = 0; half < 2; ++half){
    const u16* yb = half ? yl2 : yl;
#pragma unroll
    for (int ks = 0; ks < 2; ++ks){
      const int px = wv * 16 + l15;
      const int slot = ks * 4 + lk;
      const s16x8 af = *(const s16x8*)&yb[px * 64 + ((slot ^ (px & 7)) << 3)];
#pragma unroll
      for (int nt = 0; nt < 4; ++nt){
        const s16x8 bf = *(const s16x8*)(vt + (size_t)(nt * 16 + l15) * 64 + ks * 32 + lk * 8);
        tacc[nt] = MFMA16(af, bf, tacc[nt]);
      }
    }
  }
#pragma unroll
  for (int nt = 0; nt < 4; ++nt){
#pragma unroll
    for (int reg = 0; reg < 4; ++reg){
      const int pxm = wv * 16 + lk * 4 + reg;
      const int co = nt * 16 + l15;
      const int col = pxm + 1;
      const int elem = (66 + col) * 64 + (((co >> 3) ^ (col & 7)) << 3) + (co & 7);
      tb[(size_t)(p0 + pxm) * 64 + co] = f2bf(bf2f(xh[elem]) + tacc[nt][reg]);
    }
  }
}

// ---------------- 3x3 conv: MFMA implicit GEMM, B double-buffered in LDS ----------------
// TROWS output rows x 64 cols per block; halo (TROWS+2) x 66 in swizzled LDS.
// Weights pre-packed as 4KB chunks, staged via global_load_lds (2-phase pipeline).
template<int CIN, int COUT_FULL, int TROWS, bool RES, int MOUT>
__global__ __launch_bounds__(256)
void conv_mfma(const u16* __restrict__ in, const u16* __restrict__ wpk,
               const float* __restrict__ bias, const u16* __restrict__ res,
               void* __restrict__ out, const uint32* __restrict__ flag)
{
  if (MOUT >= 0){ if (*flag != (uint32)MOUT) return; }
  constexpr int KS  = CIN / 32;
  constexpr int TOT = 9 * KS;
  constexpr int HR  = TROWS + 2;
  constexpr int WPR = (TROWS == 4) ? 1 : (TROWS == 2 ? 2 : 4);  // waves per row
  constexpr int AT  = 4 / WPR;                                   // 16px a-tiles per wave
  __shared__ __align__(16) u16 xh[HR * 66 * CIN];
  __shared__ __align__(16) u16 Bb[2][2048];

  constexpr int RT = 128 / TROWS;
  const int bx  = blockIdx.x;
  const int img = bx / (RT * 2);
  const int rem = bx - img * (RT * 2);
  const int h0  = (rem >> 1) * TROWS;
  const int w0  = (rem & 1) * 64;
  const int co0 = blockIdx.y * 64;
  const u16* __restrict__ wp = wpk + (size_t)blockIdx.y * TOT * 2048;

  stage_tile<HR, CIN>(in + (size_t)img * 16384 * CIN, h0, w0, xh);

  auto stageB = [&](int it, int buf){
    const char* g = (const char*)(wp + (size_t)it * 2048) + threadIdx.x * 16;
    char* l = (char*)&Bb[buf][0] + threadIdx.x * 16;
    __builtin_amdgcn_global_load_lds((const __attribute__((address_space(1))) void*)g,
                                     (__attribute__((address_space(3))) void*)l, 16, 0, 0);
  };
  stageB(0, 0);
  __syncthreads();

  const int lane = threadIdx.x & 63, wv = threadIdx.x >> 6;
  const int l15 = lane & 15, lk = lane >> 4;
  const int r   = wv / WPR;
  const int c0l = (wv % WPR) * (AT * 16);

  f32x4 acc[AT][4];
#pragma unroll
  for (int nt = 0; nt < 4; ++nt){
    const float b = bias[co0 + nt * 16 + l15];
#pragma unroll
    for (int at = 0; at < AT; ++at) acc[at][nt] = (f32x4){b, b, b, b};
  }

  int cur = 0;
#pragma unroll 1
  for (int it = 0; it < TOT; ++it){
    if (it + 1 < TOT) stageB(it + 1, cur ^ 1);
    const int tap = it / KS, ks = it - tap * KS;
    const int tr = tap / 3, tc = tap - tr * 3;
    const int slot = ks * 4 + lk;
    s16x8 av[AT], bv[4];
#pragma unroll
    for (int at = 0; at < AT; ++at){
      const int col = c0l + at * 16 + l15 + tc;
      av[at] = *(const s16x8*)&xh[((r + tr) * 66 + col) * CIN + ((slot ^ (col & 7)) << 3)];
    }
#pragma unroll
    for (int nt = 0; nt < 4; ++nt){
      const int co = nt * 16 + l15;
      bv[nt] = *(const s16x8*)&Bb[cur][co * 32 + ((lk ^ ((co >> 1) & 3)) << 3)];
    }
#pragma unroll
    for (int at = 0; at < AT; ++at)
#pragma unroll
      for (int nt = 0; nt < 4; ++nt)
        acc[at][nt] = MFMA16(av[at], bv[nt], acc[at][nt]);
    asm volatile("s_waitcnt vmcnt(0)" ::: "memory");
    __syncthreads();
    cur ^= 1;
  }

#pragma unroll
  for (int at = 0; at < AT; ++at){
#pragma unroll
    for (int nt = 0; nt < 4; ++nt){
#pragma unroll
      for (int reg = 0; reg < 4; ++reg){
        float v = fmaxf(acc[at][nt][reg], 0.f);
        const int pxg = img * 16384 + (h0 + r) * 128 + w0 + c0l + at * 16 + lk * 4 + reg;
        const int co  = co0 + nt * 16 + l15;
        const size_t oi = (size_t)pxg * COUT_FULL + co;
        if (RES) v += bf2f(res[oi]);
        if (MOUT == 0) ((float*)out)[oi] = v;
        else           ((u16*)out)[oi]   = f2bf(v);
      }
    }
  }
}

extern "C" void kernel_launch(void* const* d_in, const int* in_sizes, int n_in,
                              void* d_out, int out_size, void* d_ws, size_t ws_size,
                              hipStream_t stream)
{
  (void)in_sizes; (void)n_in; (void)out_size; (void)ws_size;

  char* ws = (char*)d_ws;
  float*  wblob = (float*)ws;                            // 196864 f32
  uint32* flag  = (uint32*)(ws + 983040);
  u16*    bb    = (u16*)(ws + (1u << 20));               // bf16 blob (196608)
  u16*    gt   = bb;                                     // [2][64][64] hi/lo
  u16*    vt   = bb + 8192;                              // [64][64]
  u16*    w1pk = bb + 12288;                             // 18 x 4KB chunks
  u16*    w2pk = bb + 49152;                             // 2 x 18 x 4KB
  u16*    w3pk = bb + 122880;                            // 36 x 4KB

  u16* xb = (u16*)(ws + (size_t)2097152);                // 16.78 MB (bf16 x)
  u16* c2 = xb;                                          // reuses xb + tail (33.55 MB)
  u16* tb = (u16*)(ws + (size_t)35651584);               // 16.78 MB
  u16* c1 = (u16*)(ws + (size_t)52428800);               // 16.78 MB (ends 69.2 MB)

  detect_k<<<1, 64, 0, stream>>>((const uint32*)d_in[0], flag);

  cvtall_k<0><<<769, 256, 0, stream>>>(d_in[1], d_in[2], d_in[3], d_in[4], d_in[5],
                                       d_in[6], d_in[7], d_in[8], d_in[9], wblob, flag);
  cvtall_k<1><<<769, 256, 0, stream>>>(d_in[1], d_in[2], d_in[3], d_in[4], d_in[5],
                                       d_in[6], d_in[7], d_in[8], d_in[9], wblob, flag);

  xcvt_k<0><<<4096, 256, 0, stream>>>(d_in[0], xb, flag);
  xcvt_k<1><<<4096, 256, 0, stream>>>(d_in[0], xb, flag);

  gcomp_k<<<16, 256, 0, stream>>>(wblob, gt);
  pack_k<<<736, 256, 0, stream>>>(wblob, bb);

  attn_mfma<<<2048, 256, 0, stream>>>(xb, gt, vt, tb);

  conv_mfma<64, 64, 4, false, -1><<<dim3(512, 1), 256, 0, stream>>>(
      tb, w1pk, wblob + 49152, nullptr, c1, flag);
  conv_mfma<64, 128, 4, false, -1><<<dim3(512, 2), 256, 0, stream>>>(
      c1, w2pk, wblob + 122944, nullptr, c2, flag);
  conv_mfma<128, 64, 1, true, 0><<<dim3(2048, 1), 256, 0, stream>>>(
      c2, w3pk, wblob + 196800, tb, d_out, flag);
  conv_mfma<128, 64, 1, true, 1><<<dim3(2048, 1), 256, 0, stream>>>(
      c2, w3pk, wblob + 196800, tb, d_out, flag);
}

// Round 6
// 209.134 us; speedup vs baseline: 4.8007x; 1.0171x over previous
//
#include <hip/hip_runtime.h>

typedef unsigned int uint32;
typedef unsigned short u16;
typedef short s16x8 __attribute__((ext_vector_type(8)));
typedef float f32x4 __attribute__((ext_vector_type(4)));

#define DEVINL static __device__ __forceinline__
#define MFMA16(a, b, c) __builtin_amdgcn_mfma_f32_16x16x32_bf16(a, b, c, 0, 0, 0)

DEVINL float bf2f(u16 u){ return __uint_as_float(((uint32)u) << 16); }
DEVINL u16 f2bf(float f){
  uint32 u = __float_as_uint(f);
  u += 0x7fffu + ((u >> 16) & 1u);   // RNE
  return (u16)(u >> 16);
}
DEVINL uint32 pack2(float a, float b){
  return (uint32)f2bf(a) | (((uint32)f2bf(b)) << 16);
}

// ---------------- dtype detector (proven) ----------------
__global__ void detect_k(const uint32* __restrict__ x, uint32* __restrict__ flag){
  const int lane = threadIdx.x;   // 64 threads
  int sane = 0;
  for (int i = 0; i < 32; ++i){
    uint32 u = x[i * 64 + lane];
    uint32 e = (u >> 7) & 0xffu;
    sane += (e >= 100u && e <= 150u) ? 1 : 0;
  }
  for (int off = 32; off >= 1; off >>= 1) sane += __shfl_xor(sane, off);
  if (lane == 0) *flag = (sane > 1024) ? 1u : 0u;   // 1 = bf16, 0 = fp32
}

// ---------------- all weights -> f32 blob (proven) ----------------
template<int M>
__global__ void cvtall_k(const void* s0, const void* s1, const void* s2,
                         const void* s3, const void* s4, const void* s5,
                         const void* s6, const void* s7, const void* s8,
                         float* __restrict__ wb, const uint32* __restrict__ flag)
{
  if (*flag != (uint32)M) return;
  const int i = blockIdx.x * 256 + threadIdx.x;
  if (i >= 196864) return;
  const void* s; int j;
  if      (i < 4096)   { s = s0; j = i; }
  else if (i < 8192)   { s = s1; j = i - 4096; }
  else if (i < 12288)  { s = s2; j = i - 8192; }
  else if (i < 49152)  { s = s3; j = i - 12288; }
  else if (i < 49216)  { s = s4; j = i - 49152; }
  else if (i < 122944) { s = s5; j = i - 49216; }
  else if (i < 123072) { s = s6; j = i - 122944; }
  else if (i < 196800) { s = s7; j = i - 123072; }
  else                 { s = s8; j = i - 196800; }
  wb[i] = M ? bf2f(((const u16*)s)[j]) : ((const float*)s)[j];
}

// ---------------- x -> bf16 copy/convert ----------------
template<int M>
__global__ __launch_bounds__(256)
void xcvt_k(const void* __restrict__ x, u16* __restrict__ xb,
            const uint32* __restrict__ flag)
{
  if (*flag != (uint32)M) return;
  const size_t i0 = ((size_t)blockIdx.x * 256 + threadIdx.x) * 8;
  if (M){
    *(uint4*)(xb + i0) = *(const uint4*)((const u16*)x + i0);
  } else {
    const float4 f0 = ((const float4*)x)[i0 / 4];
    const float4 f1 = ((const float4*)x)[i0 / 4 + 1];
    uint4 o;
    o.x = pack2(f0.x, f0.y); o.y = pack2(f0.z, f0.w);
    o.z = pack2(f1.x, f1.y); o.w = pack2(f1.z, f1.w);
    *(uint4*)(xb + i0) = o;
  }
}

// ---------------- G = K_P @ Q_P^T -> hi/lo bf16 split ----------------
__global__ void gcomp_k(const float* __restrict__ wb, u16* __restrict__ gt){
  const int t = blockIdx.x * 256 + threadIdx.x;   // 4096
  const int d = t >> 6, c = t & 63;
  const float* __restrict__ K = wb + 4096;
  const float* __restrict__ Q = wb;
  float s = 0.f;
#pragma unroll
  for (int e = 0; e < 64; ++e) s = fmaf(K[d * 64 + e], Q[c * 64 + e], s);
  const u16 hi = f2bf(s);
  gt[t] = hi;
  gt[4096 + t] = f2bf(s - bf2f(hi));
}

// ---------------- pack vt + K-chunked, bank-swizzled conv weights ----------------
// wNpk layout: [chunk][co(64)][kk'(32)], chunk = tap*KS+ks, 4KB each;
// stored kk' has slot' = slot ^ ((co>>1)&3)  (slot = kk>>3).
__global__ void pack_k(const float* __restrict__ wb, u16* __restrict__ bb){
  int i = blockIdx.x * 256 + threadIdx.x;   // grid exact: 188416
  if (i < 4096){                                      // vt[o][c] = V[c][o]
    const int o = i >> 6, c = i & 63;
    bb[8192 + i] = f2bf(wb[8192 + c * 64 + o]);
    return;
  }
  i -= 4096;
  if (i < 36864){                                     // w1pk (18 chunks)
    const int chunk = i >> 11, rr = i & 2047, co = rr >> 5, kkp = rr & 31;
    const int slot = (kkp >> 3) ^ ((co >> 1) & 3), kk = slot * 8 + (kkp & 7);
    const int tap = chunk >> 1, ci = (chunk & 1) * 32 + kk;
    bb[12288 + i] = f2bf(wb[12288 + (tap * 64 + ci) * 64 + co]);
    return;
  }
  i -= 36864;
  if (i < 73728){                                     // w2pk [2 halves][18 chunks]
    const int half = i / 36864, i2 = i - half * 36864;
    const int chunk = i2 >> 11, rr = i2 & 2047, co = rr >> 5, kkp = rr & 31;
    const int slot = (kkp >> 3) ^ ((co >> 1) & 3), kk = slot * 8 + (kkp & 7);
    const int tap = chunk >> 1, ci = (chunk & 1) * 32 + kk;
    bb[49152 + i] = f2bf(wb[49216 + (tap * 64 + ci) * 128 + half * 64 + co]);
    return;
  }
  i -= 73728;
  {                                                   // w3pk (36 chunks)
    const int chunk = i >> 11, rr = i & 2047, co = rr >> 5, kkp = rr & 31;
    const int slot = (kkp >> 3) ^ ((co >> 1) & 3), kk = slot * 8 + (kkp & 7);
    const int tap = chunk >> 2, ci = (chunk & 3) * 32 + kk;
    bb[122880 + i] = f2bf(wb[123072 + (tap * 128 + ci) * 64 + co]);
  }
}

// ---------------- halo staging into swizzled LDS ----------------
// element ci of (row,col) lives at (row*66+col)*CIN + ((ci>>3)^(col&7))*8 + (ci&7)
template<int ROWS, int CIN>
DEVINL void stage_tile(const u16* __restrict__ img_base, int h0, int w0, u16* lds){
  constexpr int CH8 = CIN / 8;
  constexpr int NCH = ROWS * 66 * CH8;
  for (int idx = threadIdx.x; idx < NCH; idx += 256){
    const int row  = idx / (66 * CH8);
    const int rem  = idx - row * 66 * CH8;
    const int col  = rem / CH8;
    const int slot = rem - col * CH8;
    const int hi = h0 + row - 1, wi = w0 + col - 1;
    uint4 v = make_uint4(0u, 0u, 0u, 0u);
    if (hi >= 0 && hi < 128 && wi >= 0 && wi < 128)
      v = *(const uint4*)(img_base + (size_t)(hi * 128 + wi) * CIN + slot * 8);
    const int dst = (row * 66 + col) * CIN + ((slot ^ (col & 7)) << 3);
    *(uint4*)(lds + dst) = v;
  }
}

// ---------------- fused 3x3 pixel attention (MFMA, hi/lo G and y) — proven ----------------
__global__ __launch_bounds__(256)
void attn_mfma(const u16* __restrict__ xb, const u16* __restrict__ gt,
               const u16* __restrict__ vt, u16* __restrict__ tb)
{
  __shared__ __align__(16) u16 xh[3 * 66 * 64];
  __shared__ __align__(16) u16 yl[64 * 64];
  __shared__ __align__(16) u16 yl2[64 * 64];
  const int bx = blockIdx.x;
  const int img = bx >> 8, h = (bx >> 1) & 127, w0 = (bx & 1) * 64;
  const int p0 = img * 16384 + h * 128 + w0;
  stage_tile<3, 64>(xb + (size_t)img * 16384 * 64, h, w0, xh);
  __syncthreads();

  const int lane = threadIdx.x & 63, wv = threadIdx.x >> 6;
  const int l15 = lane & 15, lk = lane >> 4;

  f32x4 racc[4];
#pragma unroll
  for (int nt = 0; nt < 4; ++nt) racc[nt] = (f32x4){0.f, 0.f, 0.f, 0.f};
#pragma unroll
  for (int half = 0; half < 2; ++half){
#pragma unroll
    for (int ks = 0; ks < 2; ++ks){
      const int pxl = wv * 16 + l15;
      const int col = pxl + 1;
      const int slot = ks * 4 + lk;
      const s16x8 af = *(const s16x8*)&xh[(66 + col) * 64 + ((slot ^ (col & 7)) << 3)];
#pragma unroll
      for (int nt = 0; nt < 4; ++nt){
        const s16x8 bf = *(const s16x8*)(gt + half * 4096 +
                          (size_t)(nt * 16 + l15) * 64 + ks * 32 + lk * 8);
        racc[nt] = MFMA16(af, bf, racc[nt]);
      }
    }
  }

  float alpha[4][9];
#pragma unroll
  for (int reg = 0; reg < 4; ++reg){
    const int pxm = wv * 16 + lk * 4 + reg;
#pragma unroll
    for (int n = 0; n < 9; ++n){
      const int tr = n / 3, tc = n % 3;
      const int col = pxm + tc;
      float s = 0.f;
#pragma unroll
      for (int nt = 0; nt < 4; ++nt){
        const int e = nt * 16 + l15;
        const int elem = (tr * 66 + col) * 64 + (((e >> 3) ^ (col & 7)) << 3) + (e & 7);
        s = fmaf(bf2f(xh[elem]), racc[nt][reg], s);
      }
      s += __shfl_xor(s, 1); s += __shfl_xor(s, 2);
      s += __shfl_xor(s, 4); s += __shfl_xor(s, 8);
      alpha[reg][n] = s;
    }
    float mx = alpha[reg][0];
#pragma unroll
    for (int n = 1; n < 9; ++n) mx = fmaxf(mx, alpha[reg][n]);
    float sum = 0.f;
#pragma unroll
    for (int n = 0; n < 9; ++n){
      const float e = __expf(alpha[reg][n] - mx);
      alpha[reg][n] = e; sum += e;
    }
    const float inv = 1.f / sum;
#pragma unroll
    for (int n = 0; n < 9; ++n) alpha[reg][n] *= inv;
  }

#pragma unroll
  for (int reg = 0; reg < 4; ++reg){
    const int pxm = wv * 16 + lk * 4 + reg;
#pragma unroll
    for (int nt = 0; nt < 4; ++nt){
      const int e = nt * 16 + l15;
      float y = 0.f;
#pragma unroll
      for (int n = 0; n < 9; ++n){
        const int tr = n / 3, tc = n % 3;
        const int col = pxm + tc;
        const int elem = (tr * 66 + col) * 64 + (((e >> 3) ^ (col & 7)) << 3) + (e & 7);
        y = fmaf(alpha[reg][n], bf2f(xh[elem]), y);
      }
      const u16 hi = f2bf(y);
      const int idx = pxm * 64 + (((e >> 3) ^ (pxm & 7)) << 3) + (e & 7);
      yl[idx]  = hi;
      yl2[idx] = f2bf(y - bf2f(hi));
    }
  }
  __syncthreads();

  f32x4 tacc[4];
#pragma unroll
  for (int nt = 0; nt < 4; ++nt) tacc[nt] = (f32x4){0.f, 0.f, 0.f, 0.f};
#pragma unroll
  for (int half = 0; half < 2; ++half){
    const u16* yb = half ? yl2 : yl;
#pragma unroll
    for (int ks = 0; ks < 2; ++ks){
      const int px = wv * 16 + l15;
      const int slot = ks * 4 + lk;
      const s16x8 af = *(const s16x8*)&yb[px * 64 + ((slot ^ (px & 7)) << 3)];
#pragma unroll
      for (int nt = 0; nt < 4; ++nt){
        const s16x8 bf = *(const s16x8*)(vt + (size_t)(nt * 16 + l15) * 64 + ks * 32 + lk * 8);
        tacc[nt] = MFMA16(af, bf, tacc[nt]);
      }
    }
  }
#pragma unroll
  for (int nt = 0; nt < 4; ++nt){
#pragma unroll
    for (int reg = 0; reg < 4; ++reg){
      const int pxm = wv * 16 + lk * 4 + reg;
      const int co = nt * 16 + l15;
      const int col = pxm + 1;
      const int elem = (66 + col) * 64 + (((co >> 3) ^ (col & 7)) << 3) + (co & 7);
      tb[(size_t)(p0 + pxm) * 64 + co] = f2bf(bf2f(xh[elem]) + tacc[nt][reg]);
    }
  }
}

// ---------------- 3x3 conv: MFMA implicit GEMM, counted-vmcnt pipelined B ----------------
// TROWS output rows x 64 cols per block; halo (TROWS+2) x 66 in swizzled LDS.
// B: 4KB chunks, 3 LDS buffers, depth-1 prefetch. Per K-step: stage(it+1) early,
// s_waitcnt vmcnt(1) (never drain), raw s_barrier. No vmcnt(0) in the loop.
template<int CIN, int COUT_FULL, int TROWS, bool RES, int MOUT>
__global__ __launch_bounds__(256)
void conv_mfma(const u16* __restrict__ in, const u16* __restrict__ wpk,
               const float* __restrict__ bias, const u16* __restrict__ res,
               void* __restrict__ out, const uint32* __restrict__ flag)
{
  if (MOUT >= 0){ if (*flag != (uint32)MOUT) return; }
  constexpr int KS  = CIN / 32;
  constexpr int TOT = 9 * KS;
  constexpr int HR  = TROWS + 2;
  constexpr int WPR = (TROWS == 4) ? 1 : (TROWS == 2 ? 2 : 4);  // waves per row
  constexpr int AT  = 4 / WPR;                                   // 16px a-tiles per wave
  __shared__ __align__(16) u16 xh[HR * 66 * CIN];
  __shared__ __align__(16) u16 Bb[3][2048];

  constexpr int RT = 128 / TROWS;
  const int bx  = blockIdx.x;
  const int img = bx / (RT * 2);
  const int rem = bx - img * (RT * 2);
  const int h0  = (rem >> 1) * TROWS;
  const int w0  = (rem & 1) * 64;
  const int co0 = blockIdx.y * 64;
  const u16* __restrict__ wp = wpk + (size_t)blockIdx.y * TOT * 2048;

  auto stageB = [&](int it, int buf){
    const char* g = (const char*)(wp + (size_t)it * 2048) + threadIdx.x * 16;
    char* l = (char*)&Bb[buf][0] + threadIdx.x * 16;
    __builtin_amdgcn_global_load_lds((const __attribute__((address_space(1))) void*)g,
                                     (__attribute__((address_space(3))) void*)l, 16, 0, 0);
  };

  stage_tile<HR, CIN>(in + (size_t)img * 16384 * CIN, h0, w0, xh);
  stageB(0, 0);
  __syncthreads();   // full drain once: halo + chunk 0 resident

  const int lane = threadIdx.x & 63, wv = threadIdx.x >> 6;
  const int l15 = lane & 15, lk = lane >> 4;
  const int r   = wv / WPR;
  const int c0l = (wv % WPR) * (AT * 16);

  f32x4 acc[AT][4];
#pragma unroll
  for (int nt = 0; nt < 4; ++nt){
    const float b = bias[co0 + nt * 16 + l15];
#pragma unroll
    for (int at = 0; at < AT; ++at) acc[at][nt] = (f32x4){b, b, b, b};
  }

#pragma unroll 1
  for (int it = 0; it < TOT; ++it){
    if (it + 1 < TOT){
      stageB(it + 1, (it + 1) % 3);                     // issue early (depth-1)
      asm volatile("s_waitcnt vmcnt(1)" ::: "memory");  // wait stage(it) only
    } else {
      asm volatile("s_waitcnt vmcnt(0)" ::: "memory");
    }
    __builtin_amdgcn_s_barrier();
    __builtin_amdgcn_sched_barrier(0);

    const int b = it % 3;
    const int tap = it / KS, ks = it - tap * KS;
    const int tr = tap / 3, tc = tap - tr * 3;
    const int slot = ks * 4 + lk;
    s16x8 av[AT], bv[4];
#pragma unroll
    for (int at = 0; at < AT; ++at){
      const int col = c0l + at * 16 + l15 + tc;
      av[at] = *(const s16x8*)&xh[((r + tr) * 66 + col) * CIN + ((slot ^ (col & 7)) << 3)];
    }
#pragma unroll
    for (int nt = 0; nt < 4; ++nt){
      const int co = nt * 16 + l15;
      bv[nt] = *(const s16x8*)&Bb[b][co * 32 + ((lk ^ ((co >> 1) & 3)) << 3)];
    }
#pragma unroll
    for (int at = 0; at < AT; ++at)
#pragma unroll
      for (int nt = 0; nt < 4; ++nt)
        acc[at][nt] = MFMA16(av[at], bv[nt], acc[at][nt]);
  }

#pragma unroll
  for (int at = 0; at < AT; ++at){
#pragma unroll
    for (int nt = 0; nt < 4; ++nt){
#pragma unroll
      for (int reg = 0; reg < 4; ++reg){
        float v = fmaxf(acc[at][nt][reg], 0.f);
        const int pxg = img * 16384 + (h0 + r) * 128 + w0 + c0l + at * 16 + lk * 4 + reg;
        const int co  = co0 + nt * 16 + l15;
        const size_t oi = (size_t)pxg * COUT_FULL + co;
        if (RES) v += bf2f(res[oi]);
        if (MOUT == 0) ((float*)out)[oi] = v;
        else           ((u16*)out)[oi]   = f2bf(v);
      }
    }
  }
}

extern "C" void kernel_launch(void* const* d_in, const int* in_sizes, int n_in,
                              void* d_out, int out_size, void* d_ws, size_t ws_size,
                              hipStream_t stream)
{
  (void)in_sizes; (void)n_in; (void)out_size; (void)ws_size;

  char* ws = (char*)d_ws;
  float*  wblob = (float*)ws;                            // 196864 f32
  uint32* flag  = (uint32*)(ws + 983040);
  u16*    bb    = (u16*)(ws + (1u << 20));               // bf16 blob (196608)
  u16*    gt   = bb;                                     // [2][64][64] hi/lo
  u16*    vt   = bb + 8192;                              // [64][64]
  u16*    w1pk = bb + 12288;                             // 18 x 4KB chunks
  u16*    w2pk = bb + 49152;                             // 2 x 18 x 4KB
  u16*    w3pk = bb + 122880;                            // 36 x 4KB

  u16* xb = (u16*)(ws + (size_t)2097152);                // 16.78 MB (bf16 x)
  u16* c2 = xb;                                          // reuses xb + tail (33.55 MB)
  u16* tb = (u16*)(ws + (size_t)35651584);               // 16.78 MB
  u16* c1 = (u16*)(ws + (size_t)52428800);               // 16.78 MB (ends 69.2 MB)

  detect_k<<<1, 64, 0, stream>>>((const uint32*)d_in[0], flag);

  cvtall_k<0><<<769, 256, 0, stream>>>(d_in[1], d_in[2], d_in[3], d_in[4], d_in[5],
                                       d_in[6], d_in[7], d_in[8], d_in[9], wblob, flag);
  cvtall_k<1><<<769, 256, 0, stream>>>(d_in[1], d_in[2], d_in[3], d_in[4], d_in[5],
                                       d_in[6], d_in[7], d_in[8], d_in[9], wblob, flag);

  xcvt_k<0><<<4096, 256, 0, stream>>>(d_in[0], xb, flag);
  xcvt_k<1><<<4096, 256, 0, stream>>>(d_in[0], xb, flag);

  gcomp_k<<<16, 256, 0, stream>>>(wblob, gt);
  pack_k<<<736, 256, 0, stream>>>(wblob, bb);

  attn_mfma<<<2048, 256, 0, stream>>>(xb, gt, vt, tb);

  conv_mfma<64, 64, 4, false, -1><<<dim3(512, 1), 256, 0, stream>>>(
      tb, w1pk, wblob + 49152, nullptr, c1, flag);
  conv_mfma<64, 128, 4, false, -1><<<dim3(512, 2), 256, 0, stream>>>(
      c1, w2pk, wblob + 122944, nullptr, c2, flag);
  conv_mfma<128, 64, 1, true, 0><<<dim3(2048, 1), 256, 0, stream>>>(
      c2, w3pk, wblob + 196800, tb, d_out, flag);
  conv_mfma<128, 64, 1, true, 1><<<dim3(2048, 1), 256, 0, stream>>>(
      c2, w3pk, wblob + 196800, tb, d_out, flag);
}

// Round 7
// 164.100 us; speedup vs baseline: 6.1181x; 1.2744x over previous
//
#include <hip/hip_runtime.h>

typedef unsigned int uint32;
typedef unsigned short u16;
typedef short s16x8 __attribute__((ext_vector_type(8)));
typedef float f32x4 __attribute__((ext_vector_type(4)));

#define DEVINL static __device__ __forceinline__
#define MFMA16(a, b, c) __builtin_amdgcn_mfma_f32_16x16x32_bf16(a, b, c, 0, 0, 0)

DEVINL float bf2f(u16 u){ return __uint_as_float(((uint32)u) << 16); }
DEVINL u16 f2bf(float f){
  uint32 u = __float_as_uint(f);
  u += 0x7fffu + ((u >> 16) & 1u);   // RNE
  return (u16)(u >> 16);
}
DEVINL uint32 pack2(float a, float b){
  return (uint32)f2bf(a) | (((uint32)f2bf(b)) << 16);
}

// ---------------- dtype detector (proven) ----------------
__global__ void detect_k(const uint32* __restrict__ x, uint32* __restrict__ flag){
  const int lane = threadIdx.x;   // 64 threads
  int sane = 0;
  for (int i = 0; i < 32; ++i){
    uint32 u = x[i * 64 + lane];
    uint32 e = (u >> 7) & 0xffu;
    sane += (e >= 100u && e <= 150u) ? 1 : 0;
  }
  for (int off = 32; off >= 1; off >>= 1) sane += __shfl_xor(sane, off);
  if (lane == 0) *flag = (sane > 1024) ? 1u : 0u;   // 1 = bf16, 0 = fp32
}

// ---------------- all weights -> f32 blob (proven) ----------------
template<int M>
__global__ void cvtall_k(const void* s0, const void* s1, const void* s2,
                         const void* s3, const void* s4, const void* s5,
                         const void* s6, const void* s7, const void* s8,
                         float* __restrict__ wb, const uint32* __restrict__ flag)
{
  if (*flag != (uint32)M) return;
  const int i = blockIdx.x * 256 + threadIdx.x;
  if (i >= 196864) return;
  const void* s; int j;
  if      (i < 4096)   { s = s0; j = i; }
  else if (i < 8192)   { s = s1; j = i - 4096; }
  else if (i < 12288)  { s = s2; j = i - 8192; }
  else if (i < 49152)  { s = s3; j = i - 12288; }
  else if (i < 49216)  { s = s4; j = i - 49152; }
  else if (i < 122944) { s = s5; j = i - 49216; }
  else if (i < 123072) { s = s6; j = i - 122944; }
  else if (i < 196800) { s = s7; j = i - 123072; }
  else                 { s = s8; j = i - 196800; }
  wb[i] = M ? bf2f(((const u16*)s)[j]) : ((const float*)s)[j];
}

// ---------------- x -> bf16 copy/convert ----------------
template<int M>
__global__ __launch_bounds__(256)
void xcvt_k(const void* __restrict__ x, u16* __restrict__ xb,
            const uint32* __restrict__ flag)
{
  if (*flag != (uint32)M) return;
  const size_t i0 = ((size_t)blockIdx.x * 256 + threadIdx.x) * 8;
  if (M){
    *(uint4*)(xb + i0) = *(const uint4*)((const u16*)x + i0);
  } else {
    const float4 f0 = ((const float4*)x)[i0 / 4];
    const float4 f1 = ((const float4*)x)[i0 / 4 + 1];
    uint4 o;
    o.x = pack2(f0.x, f0.y); o.y = pack2(f0.z, f0.w);
    o.z = pack2(f1.x, f1.y); o.w = pack2(f1.z, f1.w);
    *(uint4*)(xb + i0) = o;
  }
}

// ---------------- G = K_P @ Q_P^T -> hi/lo bf16 split ----------------
__global__ void gcomp_k(const float* __restrict__ wb, u16* __restrict__ gt){
  const int t = blockIdx.x * 256 + threadIdx.x;   // 4096
  const int d = t >> 6, c = t & 63;
  const float* __restrict__ K = wb + 4096;
  const float* __restrict__ Q = wb;
  float s = 0.f;
#pragma unroll
  for (int e = 0; e < 64; ++e) s = fmaf(K[d * 64 + e], Q[c * 64 + e], s);
  const u16 hi = f2bf(s);
  gt[t] = hi;
  gt[4096 + t] = f2bf(s - bf2f(hi));
}

// ---------------- pack vt + K-chunked, bank-swizzled conv weights ----------------
// wNpk layout: [chunk][co(64)][kk'(32)], chunk = tap*KS+ks, 4KB each;
// stored kk' has slot' = slot ^ ((co>>1)&3)  (slot = kk>>3).
__global__ void pack_k(const float* __restrict__ wb, u16* __restrict__ bb){
  int i = blockIdx.x * 256 + threadIdx.x;   // grid exact: 188416
  if (i < 4096){                                      // vt[o][c] = V[c][o]
    const int o = i >> 6, c = i & 63;
    bb[8192 + i] = f2bf(wb[8192 + c * 64 + o]);
    return;
  }
  i -= 4096;
  if (i < 36864){                                     // w1pk (18 chunks)
    const int chunk = i >> 11, rr = i & 2047, co = rr >> 5, kkp = rr & 31;
    const int slot = (kkp >> 3) ^ ((co >> 1) & 3), kk = slot * 8 + (kkp & 7);
    const int tap = chunk >> 1, ci = (chunk & 1) * 32 + kk;
    bb[12288 + i] = f2bf(wb[12288 + (tap * 64 + ci) * 64 + co]);
    return;
  }
  i -= 36864;
  if (i < 73728){                                     // w2pk [2 halves][18 chunks]
    const int half = i / 36864, i2 = i - half * 36864;
    const int chunk = i2 >> 11, rr = i2 & 2047, co = rr >> 5, kkp = rr & 31;
    const int slot = (kkp >> 3) ^ ((co >> 1) & 3), kk = slot * 8 + (kkp & 7);
    const int tap = chunk >> 1, ci = (chunk & 1) * 32 + kk;
    bb[49152 + i] = f2bf(wb[49216 + (tap * 64 + ci) * 128 + half * 64 + co]);
    return;
  }
  i -= 73728;
  {                                                   // w3pk (36 chunks: tap*4 + ci_chunk)
    const int chunk = i >> 11, rr = i & 2047, co = rr >> 5, kkp = rr & 31;
    const int slot = (kkp >> 3) ^ ((co >> 1) & 3), kk = slot * 8 + (kkp & 7);
    const int tap = chunk >> 2, ci = (chunk & 3) * 32 + kk;
    bb[122880 + i] = f2bf(wb[123072 + (tap * 128 + ci) * 64 + co]);
  }
}

// ---------------- halo staging into swizzled LDS ----------------
// LDS holds CIN channels/pixel; source pixel stride = STRIDE channels.
// element ci of (row,col) lives at (row*66+col)*CIN + ((ci>>3)^(col&7))*8 + (ci&7)
template<int ROWS, int CIN, int STRIDE>
DEVINL void stage_tile(const u16* __restrict__ img_base, int h0, int w0, u16* lds){
  constexpr int CH8 = CIN / 8;
  constexpr int NCH = ROWS * 66 * CH8;
  for (int idx = threadIdx.x; idx < NCH; idx += 256){
    const int row  = idx / (66 * CH8);
    const int rem  = idx - row * 66 * CH8;
    const int col  = rem / CH8;
    const int slot = rem - col * CH8;
    const int hi = h0 + row - 1, wi = w0 + col - 1;
    uint4 v = make_uint4(0u, 0u, 0u, 0u);
    if (hi >= 0 && hi < 128 && wi >= 0 && wi < 128)
      v = *(const uint4*)(img_base + (size_t)(hi * 128 + wi) * STRIDE + slot * 8);
    const int dst = (row * 66 + col) * CIN + ((slot ^ (col & 7)) << 3);
    *(uint4*)(lds + dst) = v;
  }
}

// ---------------- fused 3x3 pixel attention (MFMA, hi/lo G and y) — proven ----------------
__global__ __launch_bounds__(256)
void attn_mfma(const u16* __restrict__ xb, const u16* __restrict__ gt,
               const u16* __restrict__ vt, u16* __restrict__ tb)
{
  __shared__ __align__(16) u16 xh[3 * 66 * 64];
  __shared__ __align__(16) u16 yl[64 * 64];
  __shared__ __align__(16) u16 yl2[64 * 64];
  const int bx = blockIdx.x;
  const int img = bx >> 8, h = (bx >> 1) & 127, w0 = (bx & 1) * 64;
  const int p0 = img * 16384 + h * 128 + w0;
  stage_tile<3, 64, 64>(xb + (size_t)img * 16384 * 64, h, w0, xh);
  __syncthreads();

  const int lane = threadIdx.x & 63, wv = threadIdx.x >> 6;
  const int l15 = lane & 15, lk = lane >> 4;

  f32x4 racc[4];
#pragma unroll
  for (int nt = 0; nt < 4; ++nt) racc[nt] = (f32x4){0.f, 0.f, 0.f, 0.f};
#pragma unroll
  for (int half = 0; half < 2; ++half){
#pragma unroll
    for (int ks = 0; ks < 2; ++ks){
      const int pxl = wv * 16 + l15;
      const int col = pxl + 1;
      const int slot = ks * 4 + lk;
      const s16x8 af = *(const s16x8*)&xh[(66 + col) * 64 + ((slot ^ (col & 7)) << 3)];
#pragma unroll
      for (int nt = 0; nt < 4; ++nt){
        const s16x8 bf = *(const s16x8*)(gt + half * 4096 +
                          (size_t)(nt * 16 + l15) * 64 + ks * 32 + lk * 8);
        racc[nt] = MFMA16(af, bf, racc[nt]);
      }
    }
  }

  float alpha[4][9];
#pragma unroll
  for (int reg = 0; reg < 4; ++reg){
    const int pxm = wv * 16 + lk * 4 + reg;
#pragma unroll
    for (int n = 0; n < 9; ++n){
      const int tr = n / 3, tc = n % 3;
      const int col = pxm + tc;
      float s = 0.f;
#pragma unroll
      for (int nt = 0; nt < 4; ++nt){
        const int e = nt * 16 + l15;
        const int elem = (tr * 66 + col) * 64 + (((e >> 3) ^ (col & 7)) << 3) + (e & 7);
        s = fmaf(bf2f(xh[elem]), racc[nt][reg], s);
      }
      s += __shfl_xor(s, 1); s += __shfl_xor(s, 2);
      s += __shfl_xor(s, 4); s += __shfl_xor(s, 8);
      alpha[reg][n] = s;
    }
    float mx = alpha[reg][0];
#pragma unroll
    for (int n = 1; n < 9; ++n) mx = fmaxf(mx, alpha[reg][n]);
    float sum = 0.f;
#pragma unroll
    for (int n = 0; n < 9; ++n){
      const float e = __expf(alpha[reg][n] - mx);
      alpha[reg][n] = e; sum += e;
    }
    const float inv = 1.f / sum;
#pragma unroll
    for (int n = 0; n < 9; ++n) alpha[reg][n] *= inv;
  }

#pragma unroll
  for (int reg = 0; reg < 4; ++reg){
    const int pxm = wv * 16 + lk * 4 + reg;
#pragma unroll
    for (int nt = 0; nt < 4; ++nt){
      const int e = nt * 16 + l15;
      float y = 0.f;
#pragma unroll
      for (int n = 0; n < 9; ++n){
        const int tr = n / 3, tc = n % 3;
        const int col = pxm + tc;
        const int elem = (tr * 66 + col) * 64 + (((e >> 3) ^ (col & 7)) << 3) + (e & 7);
        y = fmaf(alpha[reg][n], bf2f(xh[elem]), y);
      }
      const u16 hi = f2bf(y);
      const int idx = pxm * 64 + (((e >> 3) ^ (pxm & 7)) << 3) + (e & 7);
      yl[idx]  = hi;
      yl2[idx] = f2bf(y - bf2f(hi));
    }
  }
  __syncthreads();

  f32x4 tacc[4];
#pragma unroll
  for (int nt = 0; nt < 4; ++nt) tacc[nt] = (f32x4){0.f, 0.f, 0.f, 0.f};
#pragma unroll
  for (int half = 0; half < 2; ++half){
    const u16* yb = half ? yl2 : yl;
#pragma unroll
    for (int ks = 0; ks < 2; ++ks){
      const int px = wv * 16 + l15;
      const int slot = ks * 4 + lk;
      const s16x8 af = *(const s16x8*)&yb[px * 64 + ((slot ^ (px & 7)) << 3)];
#pragma unroll
      for (int nt = 0; nt < 4; ++nt){
        const s16x8 bf = *(const s16x8*)(vt + (size_t)(nt * 16 + l15) * 64 + ks * 32 + lk * 8);
        tacc[nt] = MFMA16(af, bf, tacc[nt]);
      }
    }
  }
#pragma unroll
  for (int nt = 0; nt < 4; ++nt){
#pragma unroll
    for (int reg = 0; reg < 4; ++reg){
      const int pxm = wv * 16 + lk * 4 + reg;
      const int co = nt * 16 + l15;
      const int col = pxm + 1;
      const int elem = (66 + col) * 64 + (((co >> 3) ^ (col & 7)) << 3) + (co & 7);
      tb[(size_t)(p0 + pxm) * 64 + co] = f2bf(bf2f(xh[elem]) + tacc[nt][reg]);
    }
  }
}

// ---------------- conv1/conv2 (CIN=64): MFMA implicit GEMM, TROWS=4 ----------------
template<int COUT_FULL, bool RES, int MOUT>
__global__ __launch_bounds__(256)
void conv_mfma(const u16* __restrict__ in, const u16* __restrict__ wpk,
               const float* __restrict__ bias, const u16* __restrict__ res,
               void* __restrict__ out, const uint32* __restrict__ flag)
{
  if (MOUT >= 0){ if (*flag != (uint32)MOUT) return; }
  constexpr int TOT = 18;
  __shared__ __align__(16) u16 xh[6 * 66 * 64];
  __shared__ __align__(16) u16 Bb[3][2048];

  const int bx  = blockIdx.x;
  const int img = bx >> 6;
  const int rem = bx & 63;
  const int h0  = (rem >> 1) * 4;
  const int w0  = (rem & 1) * 64;
  const int co0 = blockIdx.y * 64;
  const u16* __restrict__ wp = wpk + (size_t)blockIdx.y * TOT * 2048;

  auto stageB = [&](int it, int buf){
    const char* g = (const char*)(wp + (size_t)it * 2048) + threadIdx.x * 16;
    char* l = (char*)&Bb[buf][0] + threadIdx.x * 16;
    __builtin_amdgcn_global_load_lds((const __attribute__((address_space(1))) void*)g,
                                     (__attribute__((address_space(3))) void*)l, 16, 0, 0);
  };

  stage_tile<6, 64, 64>(in + (size_t)img * 16384 * 64, h0, w0, xh);
  stageB(0, 0);
  __syncthreads();

  const int lane = threadIdx.x & 63, wv = threadIdx.x >> 6;
  const int l15 = lane & 15, lk = lane >> 4;

  f32x4 acc[4][4];
#pragma unroll
  for (int nt = 0; nt < 4; ++nt){
    const float b = bias[co0 + nt * 16 + l15];
#pragma unroll
    for (int at = 0; at < 4; ++at) acc[at][nt] = (f32x4){b, b, b, b};
  }

#pragma unroll 1
  for (int it = 0; it < TOT; ++it){
    if (it + 1 < TOT){
      stageB(it + 1, (it + 1) % 3);
      asm volatile("s_waitcnt vmcnt(1)" ::: "memory");
    } else {
      asm volatile("s_waitcnt vmcnt(0)" ::: "memory");
    }
    __builtin_amdgcn_s_barrier();
    __builtin_amdgcn_sched_barrier(0);

    const int b = it % 3;
    const int tap = it >> 1, ks = it & 1;
    const int tr = tap / 3, tc = tap - tr * 3;
    const int slot = ks * 4 + lk;
    s16x8 av[4], bv[4];
#pragma unroll
    for (int at = 0; at < 4; ++at){
      const int col = at * 16 + l15 + tc;
      av[at] = *(const s16x8*)&xh[((wv + tr) * 66 + col) * 64 + ((slot ^ (col & 7)) << 3)];
    }
#pragma unroll
    for (int nt = 0; nt < 4; ++nt){
      const int co = nt * 16 + l15;
      bv[nt] = *(const s16x8*)&Bb[b][co * 32 + ((lk ^ ((co >> 1) & 3)) << 3)];
    }
#pragma unroll
    for (int at = 0; at < 4; ++at)
#pragma unroll
      for (int nt = 0; nt < 4; ++nt)
        acc[at][nt] = MFMA16(av[at], bv[nt], acc[at][nt]);
  }

#pragma unroll
  for (int at = 0; at < 4; ++at){
#pragma unroll
    for (int nt = 0; nt < 4; ++nt){
#pragma unroll
      for (int reg = 0; reg < 4; ++reg){
        float v = fmaxf(acc[at][nt][reg], 0.f);
        const int pxg = img * 16384 + (h0 + wv) * 128 + w0 + at * 16 + lk * 4 + reg;
        const int co  = co0 + nt * 16 + l15;
        const size_t oi = (size_t)pxg * COUT_FULL + co;
        if (RES) v += bf2f(res[oi]);
        if (MOUT == 0) ((float*)out)[oi] = v;
        else           ((u16*)out)[oi]   = f2bf(v);
      }
    }
  }
}

// ---------------- conv3 (CIN=128): TROWS=4 via two-phase ci-half staging ----------------
// Phase h stages halo channels [h*64, h*64+64) (6x66x64 LDS) and runs 18 K-steps;
// acc persists across phases. w3pk chunk id = tap*4 + half*2 + ks2.
template<int MOUT>
__global__ __launch_bounds__(256)
void conv3_mfma(const u16* __restrict__ in, const u16* __restrict__ wpk,
                const float* __restrict__ bias, const u16* __restrict__ res,
                void* __restrict__ out, const uint32* __restrict__ flag)
{
  if (*flag != (uint32)MOUT) return;
  __shared__ __align__(16) u16 xh[6 * 66 * 64];
  __shared__ __align__(16) u16 Bb[3][2048];

  const int bx  = blockIdx.x;
  const int img = bx >> 6;
  const int rem = bx & 63;
  const int h0  = (rem >> 1) * 4;
  const int w0  = (rem & 1) * 64;

  auto stageB = [&](int chunk, int buf){
    const char* g = (const char*)(wpk + (size_t)chunk * 2048) + threadIdx.x * 16;
    char* l = (char*)&Bb[buf][0] + threadIdx.x * 16;
    __builtin_amdgcn_global_load_lds((const __attribute__((address_space(1))) void*)g,
                                     (__attribute__((address_space(3))) void*)l, 16, 0, 0);
  };

  const int lane = threadIdx.x & 63, wv = threadIdx.x >> 6;
  const int l15 = lane & 15, lk = lane >> 4;

  f32x4 acc[4][4];
#pragma unroll
  for (int nt = 0; nt < 4; ++nt){
    const float b = bias[nt * 16 + l15];
#pragma unroll
    for (int at = 0; at < 4; ++at) acc[at][nt] = (f32x4){b, b, b, b};
  }

#pragma unroll 1
  for (int half = 0; half < 2; ++half){
    if (half) __syncthreads();        // all reads of phase-0 xh complete
    stage_tile<6, 64, 128>(in + (size_t)img * 16384 * 128 + half * 64, h0, w0, xh);
    stageB(half * 2, 0);              // chunk for tap0, ks2=0
    __syncthreads();

#pragma unroll 1
    for (int it = 0; it < 18; ++it){
      if (it + 1 < 18){
        const int tap1 = (it + 1) >> 1, ks1 = (it + 1) & 1;
        stageB(tap1 * 4 + half * 2 + ks1, (it + 1) % 3);
        asm volatile("s_waitcnt vmcnt(1)" ::: "memory");
      } else {
        asm volatile("s_waitcnt vmcnt(0)" ::: "memory");
      }
      __builtin_amdgcn_s_barrier();
      __builtin_amdgcn_sched_barrier(0);

      const int b = it % 3;
      const int tap = it >> 1, ks2 = it & 1;
      const int tr = tap / 3, tc = tap - tr * 3;
      const int slot = ks2 * 4 + lk;
      s16x8 av[4], bv[4];
#pragma unroll
      for (int at = 0; at < 4; ++at){
        const int col = at * 16 + l15 + tc;
        av[at] = *(const s16x8*)&xh[((wv + tr) * 66 + col) * 64 + ((slot ^ (col & 7)) << 3)];
      }
#pragma unroll
      for (int nt = 0; nt < 4; ++nt){
        const int co = nt * 16 + l15;
        bv[nt] = *(const s16x8*)&Bb[b][co * 32 + ((lk ^ ((co >> 1) & 3)) << 3)];
      }
#pragma unroll
      for (int at = 0; at < 4; ++at)
#pragma unroll
        for (int nt = 0; nt < 4; ++nt)
          acc[at][nt] = MFMA16(av[at], bv[nt], acc[at][nt]);
    }
  }

#pragma unroll
  for (int at = 0; at < 4; ++at){
#pragma unroll
    for (int nt = 0; nt < 4; ++nt){
#pragma unroll
      for (int reg = 0; reg < 4; ++reg){
        float v = fmaxf(acc[at][nt][reg], 0.f);
        const int pxg = img * 16384 + (h0 + wv) * 128 + w0 + at * 16 + lk * 4 + reg;
        const int co  = nt * 16 + l15;
        const size_t oi = (size_t)pxg * 64 + co;
        v += bf2f(res[oi]);
        if (MOUT == 0) ((float*)out)[oi] = v;
        else           ((u16*)out)[oi]   = f2bf(v);
      }
    }
  }
}

extern "C" void kernel_launch(void* const* d_in, const int* in_sizes, int n_in,
                              void* d_out, int out_size, void* d_ws, size_t ws_size,
                              hipStream_t stream)
{
  (void)in_sizes; (void)n_in; (void)out_size; (void)ws_size;

  char* ws = (char*)d_ws;
  float*  wblob = (float*)ws;                            // 196864 f32
  uint32* flag  = (uint32*)(ws + 983040);
  u16*    bb    = (u16*)(ws + (1u << 20));               // bf16 blob (196608)
  u16*    gt   = bb;                                     // [2][64][64] hi/lo
  u16*    vt   = bb + 8192;                              // [64][64]
  u16*    w1pk = bb + 12288;                             // 18 x 4KB chunks
  u16*    w2pk = bb + 49152;                             // 2 x 18 x 4KB
  u16*    w3pk = bb + 122880;                            // 36 x 4KB

  u16* xb = (u16*)(ws + (size_t)2097152);                // 16.78 MB (bf16 x)
  u16* c2 = xb;                                          // reuses xb + tail (33.55 MB)
  u16* tb = (u16*)(ws + (size_t)35651584);               // 16.78 MB
  u16* c1 = (u16*)(ws + (size_t)52428800);               // 16.78 MB (ends 69.2 MB)

  detect_k<<<1, 64, 0, stream>>>((const uint32*)d_in[0], flag);

  cvtall_k<0><<<769, 256, 0, stream>>>(d_in[1], d_in[2], d_in[3], d_in[4], d_in[5],
                                       d_in[6], d_in[7], d_in[8], d_in[9], wblob, flag);
  cvtall_k<1><<<769, 256, 0, stream>>>(d_in[1], d_in[2], d_in[3], d_in[4], d_in[5],
                                       d_in[6], d_in[7], d_in[8], d_in[9], wblob, flag);

  xcvt_k<0><<<4096, 256, 0, stream>>>(d_in[0], xb, flag);
  xcvt_k<1><<<4096, 256, 0, stream>>>(d_in[0], xb, flag);

  gcomp_k<<<16, 256, 0, stream>>>(wblob, gt);
  pack_k<<<736, 256, 0, stream>>>(wblob, bb);

  attn_mfma<<<2048, 256, 0, stream>>>(xb, gt, vt, tb);

  conv_mfma<64, false, -1><<<dim3(512, 1), 256, 0, stream>>>(
      tb, w1pk, wblob + 49152, nullptr, c1, flag);
  conv_mfma<128, false, -1><<<dim3(512, 2), 256, 0, stream>>>(
      c1, w2pk, wblob + 122944, nullptr, c2, flag);
  conv3_mfma<0><<<512, 256, 0, stream>>>(
      c2, w3pk, wblob + 196800, tb, d_out, flag);
  conv3_mfma<1><<<512, 256, 0, stream>>>(
      c2, w3pk, wblob + 196800, tb, d_out, flag);
}

// Round 9
// 155.429 us; speedup vs baseline: 6.4594x; 1.0558x over previous
//
#include <hip/hip_runtime.h>

typedef unsigned int uint32;
typedef unsigned short u16;
typedef short s16x8 __attribute__((ext_vector_type(8)));
typedef float f32x4 __attribute__((ext_vector_type(4)));

#define DEVINL static __device__ __forceinline__
#define MFMA16(a, b, c) __builtin_amdgcn_mfma_f32_16x16x32_bf16(a, b, c, 0, 0, 0)

DEVINL float bf2f(u16 u){ return __uint_as_float(((uint32)u) << 16); }
DEVINL u16 f2bf(float f){
  uint32 u = __float_as_uint(f);
  u += 0x7fffu + ((u >> 16) & 1u);   // RNE
  return (u16)(u >> 16);
}
DEVINL uint32 pack2(float a, float b){
  return (uint32)f2bf(a) | (((uint32)f2bf(b)) << 16);
}

// ---------------- dtype detector (proven) ----------------
__global__ void detect_k(const uint32* __restrict__ x, uint32* __restrict__ flag){
  const int lane = threadIdx.x;   // 64 threads
  int sane = 0;
  for (int i = 0; i < 32; ++i){
    uint32 u = x[i * 64 + lane];
    uint32 e = (u >> 7) & 0xffu;
    sane += (e >= 100u && e <= 150u) ? 1 : 0;
  }
  for (int off = 32; off >= 1; off >>= 1) sane += __shfl_xor(sane, off);
  if (lane == 0) *flag = (sane > 1024) ? 1u : 0u;   // 1 = bf16, 0 = fp32
}

// ---------------- all weights -> f32 blob (proven) ----------------
template<int M>
__global__ void cvtall_k(const void* s0, const void* s1, const void* s2,
                         const void* s3, const void* s4, const void* s5,
                         const void* s6, const void* s7, const void* s8,
                         float* __restrict__ wb, const uint32* __restrict__ flag)
{
  if (*flag != (uint32)M) return;
  const int i = blockIdx.x * 256 + threadIdx.x;
  if (i >= 196864) return;
  const void* s; int j;
  if      (i < 4096)   { s = s0; j = i; }
  else if (i < 8192)   { s = s1; j = i - 4096; }
  else if (i < 12288)  { s = s2; j = i - 8192; }
  else if (i < 49152)  { s = s3; j = i - 12288; }
  else if (i < 49216)  { s = s4; j = i - 49152; }
  else if (i < 122944) { s = s5; j = i - 49216; }
  else if (i < 123072) { s = s6; j = i - 122944; }
  else if (i < 196800) { s = s7; j = i - 123072; }
  else                 { s = s8; j = i - 196800; }
  wb[i] = M ? bf2f(((const u16*)s)[j]) : ((const float*)s)[j];
}

// ---------------- x -> bf16 convert (fp32 mode only) ----------------
__global__ __launch_bounds__(256)
void xcvt_k(const void* __restrict__ x, u16* __restrict__ xb,
            const uint32* __restrict__ flag)
{
  if (*flag != 0u) return;
  const size_t i0 = ((size_t)blockIdx.x * 256 + threadIdx.x) * 8;
  const float4 f0 = ((const float4*)x)[i0 / 4];
  const float4 f1 = ((const float4*)x)[i0 / 4 + 1];
  uint4 o;
  o.x = pack2(f0.x, f0.y); o.y = pack2(f0.z, f0.w);
  o.z = pack2(f1.x, f1.y); o.w = pack2(f1.z, f1.w);
  *(uint4*)(xb + i0) = o;
}

// ---------------- G = K_P @ Q_P^T -> hi/lo bf16 split ----------------
__global__ void gcomp_k(const float* __restrict__ wb, u16* __restrict__ gt){
  const int t = blockIdx.x * 256 + threadIdx.x;   // 4096
  const int d = t >> 6, c = t & 63;
  const float* __restrict__ K = wb + 4096;
  const float* __restrict__ Q = wb;
  float s = 0.f;
#pragma unroll
  for (int e = 0; e < 64; ++e) s = fmaf(K[d * 64 + e], Q[c * 64 + e], s);
  const u16 hi = f2bf(s);
  gt[t] = hi;
  gt[4096 + t] = f2bf(s - bf2f(hi));
}

// ---------------- pack vt + K-chunked, bank-swizzled conv weights ----------------
__global__ void pack_k(const float* __restrict__ wb, u16* __restrict__ bb){
  int i = blockIdx.x * 256 + threadIdx.x;   // grid exact: 188416
  if (i < 4096){                                      // vt[o][c] = V[c][o]
    const int o = i >> 6, c = i & 63;
    bb[8192 + i] = f2bf(wb[8192 + c * 64 + o]);
    return;
  }
  i -= 4096;
  if (i < 36864){                                     // w1pk (18 chunks)
    const int chunk = i >> 11, rr = i & 2047, co = rr >> 5, kkp = rr & 31;
    const int slot = (kkp >> 3) ^ ((co >> 1) & 3), kk = slot * 8 + (kkp & 7);
    const int tap = chunk >> 1, ci = (chunk & 1) * 32 + kk;
    bb[12288 + i] = f2bf(wb[12288 + (tap * 64 + ci) * 64 + co]);
    return;
  }
  i -= 36864;
  if (i < 73728){                                     // w2pk [2 halves][18 chunks]
    const int half = i / 36864, i2 = i - half * 36864;
    const int chunk = i2 >> 11, rr = i2 & 2047, co = rr >> 5, kkp = rr & 31;
    const int slot = (kkp >> 3) ^ ((co >> 1) & 3), kk = slot * 8 + (kkp & 7);
    const int tap = chunk >> 1, ci = (chunk & 1) * 32 + kk;
    bb[49152 + i] = f2bf(wb[49216 + (tap * 64 + ci) * 128 + half * 64 + co]);
    return;
  }
  i -= 73728;
  {                                                   // w3pk (36 chunks: tap*4 + ci_chunk)
    const int chunk = i >> 11, rr = i & 2047, co = rr >> 5, kkp = rr & 31;
    const int slot = (kkp >> 3) ^ ((co >> 1) & 3), kk = slot * 8 + (kkp & 7);
    const int tap = chunk >> 2, ci = (chunk & 3) * 32 + kk;
    bb[122880 + i] = f2bf(wb[123072 + (tap * 128 + ci) * 64 + co]);
  }
}

// ---------------- halo staging into swizzled LDS ----------------
// element ci of (row,col) lives at (row*66+col)*CIN + ((ci>>3)^(col&7))*8 + (ci&7)
template<int ROWS, int CIN, int STRIDE>
DEVINL void stage_tile(const u16* __restrict__ img_base, int h0, int w0, u16* lds){
  constexpr int CH8 = CIN / 8;
  constexpr int NCH = ROWS * 66 * CH8;
  for (int idx = threadIdx.x; idx < NCH; idx += 256){
    const int row  = idx / (66 * CH8);
    const int rem  = idx - row * 66 * CH8;
    const int col  = rem / CH8;
    const int slot = rem - col * CH8;
    const int hi = h0 + row - 1, wi = w0 + col - 1;
    uint4 v = make_uint4(0u, 0u, 0u, 0u);
    if (hi >= 0 && hi < 128 && wi >= 0 && wi < 128)
      v = *(const uint4*)(img_base + (size_t)(hi * 128 + wi) * STRIDE + slot * 8);
    const int dst = (row * 66 + col) * CIN + ((slot ^ (col & 7)) << 3);
    *(uint4*)(lds + dst) = v;
  }
}

// ---------------- fused 3x3 pixel attention (MFMA, hi/lo G and y) ----------------
// LDS-minimized: yl/yl2 alias halo rows 0/2 after those become dead.
// Barrier discipline (round-8 race lesson): sync2 = all halo reads of rows 0/2
// done BEFORE any write; sync3 = all yl/yl2 writes done BEFORE any PV read.
__global__ __launch_bounds__(256)
void attn_mfma(const u16* __restrict__ xraw, const u16* __restrict__ xcv,
               const u16* __restrict__ gt, const u16* __restrict__ vt,
               u16* __restrict__ tb, const uint32* __restrict__ flag)
{
  __shared__ __align__(16) u16 xh[3 * 66 * 64];
  u16* yl  = xh;                   // aliases halo row 0
  u16* yl2 = xh + 2 * 66 * 64;     // aliases halo row 2
  const int bx0 = blockIdx.x;
  const int bx = (bx0 & 7) * 256 + (bx0 >> 3);   // XCD-chunked swizzle (2048 wgs)
  const int img = bx >> 8, h = (bx >> 1) & 127, w0 = (bx & 1) * 64;
  const int p0 = img * 16384 + h * 128 + w0;
  const u16* __restrict__ xsrc = (*flag != 0u) ? xraw : xcv;
  stage_tile<3, 64, 64>(xsrc + (size_t)img * 16384 * 64, h, w0, xh);
  __syncthreads();

  const int lane = threadIdx.x & 63, wv = threadIdx.x >> 6;
  const int l15 = lane & 15, lk = lane >> 4;

  f32x4 racc[4];
#pragma unroll
  for (int nt = 0; nt < 4; ++nt) racc[nt] = (f32x4){0.f, 0.f, 0.f, 0.f};
#pragma unroll
  for (int half = 0; half < 2; ++half){
#pragma unroll
    for (int ks = 0; ks < 2; ++ks){
      const int pxl = wv * 16 + l15;
      const int col = pxl + 1;
      const int slot = ks * 4 + lk;
      const s16x8 af = *(const s16x8*)&xh[(66 + col) * 64 + ((slot ^ (col & 7)) << 3)];
#pragma unroll
      for (int nt = 0; nt < 4; ++nt){
        const s16x8 bf = *(const s16x8*)(gt + half * 4096 +
                          (size_t)(nt * 16 + l15) * 64 + ks * 32 + lk * 8);
        racc[nt] = MFMA16(af, bf, racc[nt]);
      }
    }
  }

  float yv[4][4];
#pragma unroll
  for (int reg = 0; reg < 4; ++reg){
    const int pxm = wv * 16 + lk * 4 + reg;
    float alpha[9];
#pragma unroll
    for (int n = 0; n < 9; ++n){
      const int tr = n / 3, tc = n % 3;
      const int col = pxm + tc;
      float s = 0.f;
#pragma unroll
      for (int nt = 0; nt < 4; ++nt){
        const int e = nt * 16 + l15;
        const int elem = (tr * 66 + col) * 64 + (((e >> 3) ^ (col & 7)) << 3) + (e & 7);
        s = fmaf(bf2f(xh[elem]), racc[nt][reg], s);
      }
      s += __shfl_xor(s, 1); s += __shfl_xor(s, 2);
      s += __shfl_xor(s, 4); s += __shfl_xor(s, 8);
      alpha[n] = s;
    }
    float mx = alpha[0];
#pragma unroll
    for (int n = 1; n < 9; ++n) mx = fmaxf(mx, alpha[n]);
    float sum = 0.f;
#pragma unroll
    for (int n = 0; n < 9; ++n){
      const float e = __expf(alpha[n] - mx);
      alpha[n] = e; sum += e;
    }
    const float inv = 1.f / sum;
#pragma unroll
    for (int n = 0; n < 9; ++n) alpha[n] *= inv;

#pragma unroll
    for (int nt = 0; nt < 4; ++nt){
      const int e = nt * 16 + l15;
      float y = 0.f;
#pragma unroll
      for (int n = 0; n < 9; ++n){
        const int tr = n / 3, tc = n % 3;
        const int col = pxm + tc;
        const int elem = (tr * 66 + col) * 64 + (((e >> 3) ^ (col & 7)) << 3) + (e & 7);
        y = fmaf(alpha[n], bf2f(xh[elem]), y);
      }
      yv[reg][nt] = y;
    }
  }

  __syncthreads();   // sync2: all halo reads of rows 0/2 complete across waves

#pragma unroll
  for (int reg = 0; reg < 4; ++reg){
    const int pxm = wv * 16 + lk * 4 + reg;
#pragma unroll
    for (int nt = 0; nt < 4; ++nt){
      const int e = nt * 16 + l15;
      const float y = yv[reg][nt];
      const u16 hi = f2bf(y);
      const int idx = pxm * 64 + (((e >> 3) ^ (pxm & 7)) << 3) + (e & 7);
      yl[idx]  = hi;
      yl2[idx] = f2bf(y - bf2f(hi));
    }
  }

  __syncthreads();   // sync3: all yl/yl2 writes visible before any PV read

  f32x4 tacc[4];
#pragma unroll
  for (int nt = 0; nt < 4; ++nt) tacc[nt] = (f32x4){0.f, 0.f, 0.f, 0.f};
#pragma unroll
  for (int half = 0; half < 2; ++half){
    const u16* yb = half ? yl2 : yl;
#pragma unroll
    for (int ks = 0; ks < 2; ++ks){
      const int px = wv * 16 + l15;
      const int slot = ks * 4 + lk;
      const s16x8 af = *(const s16x8*)&yb[px * 64 + ((slot ^ (px & 7)) << 3)];
#pragma unroll
      for (int nt = 0; nt < 4; ++nt){
        const s16x8 bf = *(const s16x8*)(vt + (size_t)(nt * 16 + l15) * 64 + ks * 32 + lk * 8);
        tacc[nt] = MFMA16(af, bf, tacc[nt]);
      }
    }
  }
#pragma unroll
  for (int nt = 0; nt < 4; ++nt){
#pragma unroll
    for (int reg = 0; reg < 4; ++reg){
      const int pxm = wv * 16 + lk * 4 + reg;
      const int co = nt * 16 + l15;
      const int col = pxm + 1;
      const int elem = (66 + col) * 64 + (((co >> 3) ^ (col & 7)) << 3) + (co & 7);
      tb[(size_t)(p0 + pxm) * 64 + co] = f2bf(bf2f(xh[elem]) + tacc[nt][reg]);
    }
  }
}

// ---------------- conv1/conv2 (CIN=64): MFMA implicit GEMM, TROWS=4 ----------------
template<int COUT_FULL, bool RES, int MOUT>
__global__ __launch_bounds__(256)
void conv_mfma(const u16* __restrict__ in, const u16* __restrict__ wpk,
               const float* __restrict__ bias, const u16* __restrict__ res,
               void* __restrict__ out, const uint32* __restrict__ flag)
{
  if (MOUT >= 0){ if (*flag != (uint32)MOUT) return; }
  constexpr int TOT = 18;
  __shared__ __align__(16) u16 xh[6 * 66 * 64];
  __shared__ __align__(16) u16 Bb[3][2048];

  const int bx0 = blockIdx.x;
  const int bx  = (bx0 & 7) * 64 + (bx0 >> 3);   // XCD-chunked swizzle (512 wgs)
  const int img = bx >> 6;
  const int rem = bx & 63;
  const int h0  = (rem >> 1) * 4;
  const int w0  = (rem & 1) * 64;
  const int co0 = blockIdx.y * 64;
  const u16* __restrict__ wp = wpk + (size_t)blockIdx.y * TOT * 2048;

  auto stageB = [&](int it, int buf){
    const char* g = (const char*)(wp + (size_t)it * 2048) + threadIdx.x * 16;
    char* l = (char*)&Bb[buf][0] + threadIdx.x * 16;
    __builtin_amdgcn_global_load_lds((const __attribute__((address_space(1))) void*)g,
                                     (__attribute__((address_space(3))) void*)l, 16, 0, 0);
  };

  stage_tile<6, 64, 64>(in + (size_t)img * 16384 * 64, h0, w0, xh);
  stageB(0, 0);
  __syncthreads();

  const int lane = threadIdx.x & 63, wv = threadIdx.x >> 6;
  const int l15 = lane & 15, lk = lane >> 4;

  f32x4 acc[4][4];
#pragma unroll
  for (int nt = 0; nt < 4; ++nt){
    const float b = bias[co0 + nt * 16 + l15];
#pragma unroll
    for (int at = 0; at < 4; ++at) acc[at][nt] = (f32x4){b, b, b, b};
  }

#pragma unroll 1
  for (int it = 0; it < TOT; ++it){
    if (it + 1 < TOT){
      stageB(it + 1, (it + 1) % 3);
      asm volatile("s_waitcnt vmcnt(1)" ::: "memory");
    } else {
      asm volatile("s_waitcnt vmcnt(0)" ::: "memory");
    }
    __builtin_amdgcn_s_barrier();
    __builtin_amdgcn_sched_barrier(0);

    const int b = it % 3;
    const int tap = it >> 1, ks = it & 1;
    const int tr = tap / 3, tc = tap - tr * 3;
    const int slot = ks * 4 + lk;
    s16x8 av[4], bv[4];
#pragma unroll
    for (int at = 0; at < 4; ++at){
      const int col = at * 16 + l15 + tc;
      av[at] = *(const s16x8*)&xh[((wv + tr) * 66 + col) * 64 + ((slot ^ (col & 7)) << 3)];
    }
#pragma unroll
    for (int nt = 0; nt < 4; ++nt){
      const int co = nt * 16 + l15;
      bv[nt] = *(const s16x8*)&Bb[b][co * 32 + ((lk ^ ((co >> 1) & 3)) << 3)];
    }
#pragma unroll
    for (int at = 0; at < 4; ++at)
#pragma unroll
      for (int nt = 0; nt < 4; ++nt)
        acc[at][nt] = MFMA16(av[at], bv[nt], acc[at][nt]);
  }

#pragma unroll
  for (int at = 0; at < 4; ++at){
#pragma unroll
    for (int nt = 0; nt < 4; ++nt){
#pragma unroll
      for (int reg = 0; reg < 4; ++reg){
        float v = fmaxf(acc[at][nt][reg], 0.f);
        const int pxg = img * 16384 + (h0 + wv) * 128 + w0 + at * 16 + lk * 4 + reg;
        const int co  = co0 + nt * 16 + l15;
        const size_t oi = (size_t)pxg * COUT_FULL + co;
        if (RES) v += bf2f(res[oi]);
        if (MOUT == 0) ((float*)out)[oi] = v;
        else           ((u16*)out)[oi]   = f2bf(v);
      }
    }
  }
}

// ---------------- conv3 (CIN=128): TROWS=4 via two-phase ci-half staging ----------------
template<int MOUT>
__global__ __launch_bounds__(256)
void conv3_mfma(const u16* __restrict__ in, const u16* __restrict__ wpk,
                const float* __restrict__ bias, const u16* __restrict__ res,
                void* __restrict__ out, const uint32* __restrict__ flag)
{
  if (*flag != (uint32)MOUT) return;
  __shared__ __align__(16) u16 xh[6 * 66 * 64];
  __shared__ __align__(16) u16 Bb[3][2048];

  const int bx0 = blockIdx.x;
  const int bx  = (bx0 & 7) * 64 + (bx0 >> 3);   // XCD-chunked swizzle (512 wgs)
  const int img = bx >> 6;
  const int rem = bx & 63;
  const int h0  = (rem >> 1) * 4;
  const int w0  = (rem & 1) * 64;

  auto stageB = [&](int chunk, int buf){
    const char* g = (const char*)(wpk + (size_t)chunk * 2048) + threadIdx.x * 16;
    char* l = (char*)&Bb[buf][0] + threadIdx.x * 16;
    __builtin_amdgcn_global_load_lds((const __attribute__((address_space(1))) void*)g,
                                     (__attribute__((address_space(3))) void*)l, 16, 0, 0);
  };

  const int lane = threadIdx.x & 63, wv = threadIdx.x >> 6;
  const int l15 = lane & 15, lk = lane >> 4;

  f32x4 acc[4][4];
#pragma unroll
  for (int nt = 0; nt < 4; ++nt){
    const float b = bias[nt * 16 + l15];
#pragma unroll
    for (int at = 0; at < 4; ++at) acc[at][nt] = (f32x4){b, b, b, b};
  }

#pragma unroll 1
  for (int half = 0; half < 2; ++half){
    if (half) __syncthreads();
    stage_tile<6, 64, 128>(in + (size_t)img * 16384 * 128 + half * 64, h0, w0, xh);
    stageB(half * 2, 0);
    __syncthreads();

#pragma unroll 1
    for (int it = 0; it < 18; ++it){
      if (it + 1 < 18){
        const int tap1 = (it + 1) >> 1, ks1 = (it + 1) & 1;
        stageB(tap1 * 4 + half * 2 + ks1, (it + 1) % 3);
        asm volatile("s_waitcnt vmcnt(1)" ::: "memory");
      } else {
        asm volatile("s_waitcnt vmcnt(0)" ::: "memory");
      }
      __builtin_amdgcn_s_barrier();
      __builtin_amdgcn_sched_barrier(0);

      const int b = it % 3;
      const int tap = it >> 1, ks2 = it & 1;
      const int tr = tap / 3, tc = tap - tr * 3;
      const int slot = ks2 * 4 + lk;
      s16x8 av[4], bv[4];
#pragma unroll
      for (int at = 0; at < 4; ++at){
        const int col = at * 16 + l15 + tc;
        av[at] = *(const s16x8*)&xh[((wv + tr) * 66 + col) * 64 + ((slot ^ (col & 7)) << 3)];
      }
#pragma unroll
      for (int nt = 0; nt < 4; ++nt){
        const int co = nt * 16 + l15;
        bv[nt] = *(const s16x8*)&Bb[b][co * 32 + ((lk ^ ((co >> 1) & 3)) << 3)];
      }
#pragma unroll
      for (int at = 0; at < 4; ++at)
#pragma unroll
        for (int nt = 0; nt < 4; ++nt)
          acc[at][nt] = MFMA16(av[at], bv[nt], acc[at][nt]);
    }
  }

#pragma unroll
  for (int at = 0; at < 4; ++at){
#pragma unroll
    for (int nt = 0; nt < 4; ++nt){
#pragma unroll
      for (int reg = 0; reg < 4; ++reg){
        float v = fmaxf(acc[at][nt][reg], 0.f);
        const int pxg = img * 16384 + (h0 + wv) * 128 + w0 + at * 16 + lk * 4 + reg;
        const int co  = nt * 16 + l15;
        const size_t oi = (size_t)pxg * 64 + co;
        v += bf2f(res[oi]);
        if (MOUT == 0) ((float*)out)[oi] = v;
        else           ((u16*)out)[oi]   = f2bf(v);
      }
    }
  }
}

extern "C" void kernel_launch(void* const* d_in, const int* in_sizes, int n_in,
                              void* d_out, int out_size, void* d_ws, size_t ws_size,
                              hipStream_t stream)
{
  (void)in_sizes; (void)n_in; (void)out_size; (void)ws_size;

  char* ws = (char*)d_ws;
  float*  wblob = (float*)ws;                            // 196864 f32
  uint32* flag  = (uint32*)(ws + 983040);
  u16*    bb    = (u16*)(ws + (1u << 20));               // bf16 blob (196608)
  u16*    gt   = bb;                                     // [2][64][64] hi/lo
  u16*    vt   = bb + 8192;                              // [64][64]
  u16*    w1pk = bb + 12288;                             // 18 x 4KB chunks
  u16*    w2pk = bb + 49152;                             // 2 x 18 x 4KB
  u16*    w3pk = bb + 122880;                            // 36 x 4KB

  u16* xb = (u16*)(ws + (size_t)2097152);                // 16.78 MB (bf16 x, fp32 mode)
  u16* c2 = xb;                                          // reuses xb + tail (33.55 MB)
  u16* tb = (u16*)(ws + (size_t)35651584);               // 16.78 MB
  u16* c1 = (u16*)(ws + (size_t)52428800);               // 16.78 MB (ends 69.2 MB)

  detect_k<<<1, 64, 0, stream>>>((const uint32*)d_in[0], flag);

  cvtall_k<0><<<769, 256, 0, stream>>>(d_in[1], d_in[2], d_in[3], d_in[4], d_in[5],
                                       d_in[6], d_in[7], d_in[8], d_in[9], wblob, flag);
  cvtall_k<1><<<769, 256, 0, stream>>>(d_in[1], d_in[2], d_in[3], d_in[4], d_in[5],
                                       d_in[6], d_in[7], d_in[8], d_in[9], wblob, flag);

  xcvt_k<<<4096, 256, 0, stream>>>(d_in[0], xb, flag);   // fp32 mode only

  gcomp_k<<<16, 256, 0, stream>>>(wblob, gt);
  pack_k<<<736, 256, 0, stream>>>(wblob, bb);

  attn_mfma<<<2048, 256, 0, stream>>>((const u16*)d_in[0], xb, gt, vt, tb, flag);

  conv_mfma<64, false, -1><<<dim3(512, 1), 256, 0, stream>>>(
      tb, w1pk, wblob + 49152, nullptr, c1, flag);
  conv_mfma<128, false, -1><<<dim3(512, 2), 256, 0, stream>>>(
      c1, w2pk, wblob + 122944, nullptr, c2, flag);
  conv3_mfma<0><<<512, 256, 0, stream>>>(
      c2, w3pk, wblob + 196800, tb, d_out, flag);
  conv3_mfma<1><<<512, 256, 0, stream>>>(
      c2, w3pk, wblob + 196800, tb, d_out, flag);
}

// Round 10
// 152.889 us; speedup vs baseline: 6.5667x; 1.0166x over previous
//
#include <hip/hip_runtime.h>

typedef unsigned int uint32;
typedef unsigned short u16;
typedef short s16x8 __attribute__((ext_vector_type(8)));
typedef float f32x4 __attribute__((ext_vector_type(4)));

#define DEVINL static __device__ __forceinline__
#define MFMA16(a, b, c) __builtin_amdgcn_mfma_f32_16x16x32_bf16(a, b, c, 0, 0, 0)

DEVINL float bf2f(u16 u){ return __uint_as_float(((uint32)u) << 16); }
DEVINL u16 f2bf(float f){
  uint32 u = __float_as_uint(f);
  u += 0x7fffu + ((u >> 16) & 1u);   // RNE
  return (u16)(u >> 16);
}
DEVINL uint32 pack2(float a, float b){
  return (uint32)f2bf(a) | (((uint32)f2bf(b)) << 16);
}

// ---------------- dtype detector (proven) ----------------
__global__ void detect_k(const uint32* __restrict__ x, uint32* __restrict__ flag){
  const int lane = threadIdx.x;   // 64 threads
  int sane = 0;
  for (int i = 0; i < 32; ++i){
    uint32 u = x[i * 64 + lane];
    uint32 e = (u >> 7) & 0xffu;
    sane += (e >= 100u && e <= 150u) ? 1 : 0;
  }
  for (int off = 32; off >= 1; off >>= 1) sane += __shfl_xor(sane, off);
  if (lane == 0) *flag = (sane > 1024) ? 1u : 0u;   // 1 = bf16, 0 = fp32
}

// ---------------- all weights -> f32 blob (proven) ----------------
template<int M>
__global__ void cvtall_k(const void* s0, const void* s1, const void* s2,
                         const void* s3, const void* s4, const void* s5,
                         const void* s6, const void* s7, const void* s8,
                         float* __restrict__ wb, const uint32* __restrict__ flag)
{
  if (*flag != (uint32)M) return;
  const int i = blockIdx.x * 256 + threadIdx.x;
  if (i >= 196864) return;
  const void* s; int j;
  if      (i < 4096)   { s = s0; j = i; }
  else if (i < 8192)   { s = s1; j = i - 4096; }
  else if (i < 12288)  { s = s2; j = i - 8192; }
  else if (i < 49152)  { s = s3; j = i - 12288; }
  else if (i < 49216)  { s = s4; j = i - 49152; }
  else if (i < 122944) { s = s5; j = i - 49216; }
  else if (i < 123072) { s = s6; j = i - 122944; }
  else if (i < 196800) { s = s7; j = i - 123072; }
  else                 { s = s8; j = i - 196800; }
  wb[i] = M ? bf2f(((const u16*)s)[j]) : ((const float*)s)[j];
}

// ---------------- x -> bf16 convert (fp32 mode only) ----------------
__global__ __launch_bounds__(256)
void xcvt_k(const void* __restrict__ x, u16* __restrict__ xb,
            const uint32* __restrict__ flag)
{
  if (*flag != 0u) return;
  const size_t i0 = ((size_t)blockIdx.x * 256 + threadIdx.x) * 8;
  const float4 f0 = ((const float4*)x)[i0 / 4];
  const float4 f1 = ((const float4*)x)[i0 / 4 + 1];
  uint4 o;
  o.x = pack2(f0.x, f0.y); o.y = pack2(f0.z, f0.w);
  o.z = pack2(f1.x, f1.y); o.w = pack2(f1.z, f1.w);
  *(uint4*)(xb + i0) = o;
}

// ---------------- G = K_P @ Q_P^T -> hi/lo bf16 split ----------------
__global__ void gcomp_k(const float* __restrict__ wb, u16* __restrict__ gt){
  const int t = blockIdx.x * 256 + threadIdx.x;   // 4096
  const int d = t >> 6, c = t & 63;
  const float* __restrict__ K = wb + 4096;
  const float* __restrict__ Q = wb;
  float s = 0.f;
#pragma unroll
  for (int e = 0; e < 64; ++e) s = fmaf(K[d * 64 + e], Q[c * 64 + e], s);
  const u16 hi = f2bf(s);
  gt[t] = hi;
  gt[4096 + t] = f2bf(s - bf2f(hi));
}

// ---------------- pack vt + K-chunked, bank-swizzled conv weights ----------------
__global__ void pack_k(const float* __restrict__ wb, u16* __restrict__ bb){
  int i = blockIdx.x * 256 + threadIdx.x;   // grid exact: 188416
  if (i < 4096){                                      // vt[o][c] = V[c][o]
    const int o = i >> 6, c = i & 63;
    bb[8192 + i] = f2bf(wb[8192 + c * 64 + o]);
    return;
  }
  i -= 4096;
  if (i < 36864){                                     // w1pk (18 chunks)
    const int chunk = i >> 11, rr = i & 2047, co = rr >> 5, kkp = rr & 31;
    const int slot = (kkp >> 3) ^ ((co >> 1) & 3), kk = slot * 8 + (kkp & 7);
    const int tap = chunk >> 1, ci = (chunk & 1) * 32 + kk;
    bb[12288 + i] = f2bf(wb[12288 + (tap * 64 + ci) * 64 + co]);
    return;
  }
  i -= 36864;
  if (i < 73728){                                     // w2pk [2 halves][18 chunks]
    const int half = i / 36864, i2 = i - half * 36864;
    const int chunk = i2 >> 11, rr = i2 & 2047, co = rr >> 5, kkp = rr & 31;
    const int slot = (kkp >> 3) ^ ((co >> 1) & 3), kk = slot * 8 + (kkp & 7);
    const int tap = chunk >> 1, ci = (chunk & 1) * 32 + kk;
    bb[49152 + i] = f2bf(wb[49216 + (tap * 64 + ci) * 128 + half * 64 + co]);
    return;
  }
  i -= 73728;
  {                                                   // w3pk (36 chunks: tap*4 + ci_chunk)
    const int chunk = i >> 11, rr = i & 2047, co = rr >> 5, kkp = rr & 31;
    const int slot = (kkp >> 3) ^ ((co >> 1) & 3), kk = slot * 8 + (kkp & 7);
    const int tap = chunk >> 2, ci = (chunk & 3) * 32 + kk;
    bb[122880 + i] = f2bf(wb[123072 + (tap * 128 + ci) * 64 + co]);
  }
}

// ---------------- halo staging into swizzled LDS ----------------
// element ci of (row,col) lives at (row*66+col)*CIN + ((ci>>3)^(col&7))*8 + (ci&7)
template<int ROWS, int CIN, int STRIDE>
DEVINL void stage_tile(const u16* __restrict__ img_base, int h0, int w0, u16* lds){
  constexpr int CH8 = CIN / 8;
  constexpr int NCH = ROWS * 66 * CH8;
  for (int idx = threadIdx.x; idx < NCH; idx += 256){
    const int row  = idx / (66 * CH8);
    const int rem  = idx - row * 66 * CH8;
    const int col  = rem / CH8;
    const int slot = rem - col * CH8;
    const int hi = h0 + row - 1, wi = w0 + col - 1;
    uint4 v = make_uint4(0u, 0u, 0u, 0u);
    if (hi >= 0 && hi < 128 && wi >= 0 && wi < 128)
      v = *(const uint4*)(img_base + (size_t)(hi * 128 + wi) * STRIDE + slot * 8);
    const int dst = (row * 66 + col) * CIN + ((slot ^ (col & 7)) << 3);
    *(uint4*)(lds + dst) = v;
  }
}

// ---------------- fused 3x3 pixel attention ----------------
// QK via MFMA; r transposed through LDS (f32, stride 68) so the score/y phase is
// fully vectorized: lane = pixel (l15), lk = e-quarter; all x reads are b128.
// Barriers: sync1 stage; sync2 r visible; sync3 xh rows0/2 reads done before alias
// writes; sync4 y visible before PV (round-8 race lesson).
__global__ __launch_bounds__(256)
void attn_mfma(const u16* __restrict__ xraw, const u16* __restrict__ xcv,
               const u16* __restrict__ gt, const u16* __restrict__ vt,
               u16* __restrict__ tb, const uint32* __restrict__ flag)
{
  __shared__ __align__(16) u16 xh[3 * 66 * 64];
  __shared__ __align__(16) float rl[64 * 68];
  u16* yl  = xh;                   // aliases halo row 0
  u16* yl2 = xh + 2 * 66 * 64;     // aliases halo row 2
  const int bx0 = blockIdx.x;
  const int bx = (bx0 & 7) * 256 + (bx0 >> 3);   // XCD-chunked swizzle (2048 wgs)
  const int img = bx >> 8, h = (bx >> 1) & 127, w0 = (bx & 1) * 64;
  const int p0 = img * 16384 + h * 128 + w0;
  const u16* __restrict__ xsrc = (*flag != 0u) ? xraw : xcv;
  stage_tile<3, 64, 64>(xsrc + (size_t)img * 16384 * 64, h, w0, xh);
  __syncthreads();   // sync1

  const int lane = threadIdx.x & 63, wv = threadIdx.x >> 6;
  const int l15 = lane & 15, lk = lane >> 4;

  // ---- QK^T: r[p][d] = sum_c x[p][c] G[d][c], G = Ghi + Glo ----
  f32x4 racc[4];
#pragma unroll
  for (int nt = 0; nt < 4; ++nt) racc[nt] = (f32x4){0.f, 0.f, 0.f, 0.f};
#pragma unroll
  for (int half = 0; half < 2; ++half){
#pragma unroll
    for (int ks = 0; ks < 2; ++ks){
      const int pxl = wv * 16 + l15;
      const int col = pxl + 1;
      const int slot = ks * 4 + lk;
      const s16x8 af = *(const s16x8*)&xh[(66 + col) * 64 + ((slot ^ (col & 7)) << 3)];
#pragma unroll
      for (int nt = 0; nt < 4; ++nt){
        const s16x8 bf = *(const s16x8*)(gt + half * 4096 +
                          (size_t)(nt * 16 + l15) * 64 + ks * 32 + lk * 8);
        racc[nt] = MFMA16(af, bf, racc[nt]);
      }
    }
  }

  // ---- transpose r through LDS (f32, row stride 68 -> 2-way banks) ----
#pragma unroll
  for (int nt = 0; nt < 4; ++nt)
#pragma unroll
    for (int reg = 0; reg < 4; ++reg)
      rl[(wv * 16 + lk * 4 + reg) * 68 + nt * 16 + l15] = racc[nt][reg];

  __syncthreads();   // sync2: r visible to all lanes

  // ---- score/softmax/y: lane owns px = l15 (of wave tile), e-quarter = lk ----
  const int pxm = wv * 16 + l15;        // block-local pixel 0..63
  float rq[16];
  {
    const float* rr = rl + pxm * 68 + lk * 16;
#pragma unroll
    for (int j = 0; j < 16; j += 4){
      const float4 v = *(const float4*)(rr + j);
      rq[j] = v.x; rq[j+1] = v.y; rq[j+2] = v.z; rq[j+3] = v.w;
    }
  }

  float sc[9];
#pragma unroll
  for (int n = 0; n < 9; ++n){
    const int tr = n / 3, tc = n % 3;
    const int col = pxm + tc;
    const u16* xr = &xh[(tr * 66 + col) * 64];
    float s = 0.f;
#pragma unroll
    for (int sl = 0; sl < 2; ++sl){
      const int slot = lk * 2 + sl;
      const s16x8 v = *(const s16x8*)&xr[(slot ^ (col & 7)) << 3];
#pragma unroll
      for (int j = 0; j < 8; ++j)
        s = fmaf(bf2f((u16)v[j]), rq[sl * 8 + j], s);
    }
    sc[n] = s;
  }
#pragma unroll
  for (int n = 0; n < 9; ++n){
    sc[n] += __shfl_xor(sc[n], 16);
    sc[n] += __shfl_xor(sc[n], 32);
  }

  float mx = sc[0];
#pragma unroll
  for (int n = 1; n < 9; ++n) mx = fmaxf(mx, sc[n]);
  float sum = 0.f;
#pragma unroll
  for (int n = 0; n < 9; ++n){
    const float e = __expf(sc[n] - mx);
    sc[n] = e; sum += e;
  }
  const float inv = 1.f / sum;
#pragma unroll
  for (int n = 0; n < 9; ++n) sc[n] *= inv;

  float y[16];
#pragma unroll
  for (int j = 0; j < 16; ++j) y[j] = 0.f;
#pragma unroll
  for (int n = 0; n < 9; ++n){
    const int tr = n / 3, tc = n % 3;
    const int col = pxm + tc;
    const u16* xr = &xh[(tr * 66 + col) * 64];
    const float a = sc[n];
#pragma unroll
    for (int sl = 0; sl < 2; ++sl){
      const int slot = lk * 2 + sl;
      const s16x8 v = *(const s16x8*)&xr[(slot ^ (col & 7)) << 3];
#pragma unroll
      for (int j = 0; j < 8; ++j)
        y[sl * 8 + j] = fmaf(a, bf2f((u16)v[j]), y[sl * 8 + j]);
    }
  }

  __syncthreads();   // sync3: all xh row-0/2 reads complete before alias writes

#pragma unroll
  for (int sl = 0; sl < 2; ++sl){
    uint32 hwd[4], lwd[4];
#pragma unroll
    for (int j = 0; j < 4; ++j){
      const float a = y[sl * 8 + 2 * j], b = y[sl * 8 + 2 * j + 1];
      const u16 ha = f2bf(a), hb = f2bf(b);
      hwd[j] = (uint32)ha | ((uint32)hb << 16);
      lwd[j] = (uint32)f2bf(a - bf2f(ha)) | ((uint32)f2bf(b - bf2f(hb)) << 16);
    }
    const int slot = lk * 2 + sl;
    const int off = pxm * 64 + ((slot ^ (pxm & 7)) << 3);
    *(uint4*)&yl [off] = make_uint4(hwd[0], hwd[1], hwd[2], hwd[3]);
    *(uint4*)&yl2[off] = make_uint4(lwd[0], lwd[1], lwd[2], lwd[3]);
  }

  __syncthreads();   // sync4: y visible before PV reads

  // ---- PV: t = x + (yhi + ylo) @ V ----
  f32x4 tacc[4];
#pragma unroll
  for (int nt = 0; nt < 4; ++nt) tacc[nt] = (f32x4){0.f, 0.f, 0.f, 0.f};
#pragma unroll
  for (int half = 0; half < 2; ++half){
    const u16* yb = half ? yl2 : yl;
#pragma unroll
    for (int ks = 0; ks < 2; ++ks){
      const int px = wv * 16 + l15;
      const int slot = ks * 4 + lk;
      const s16x8 af = *(const s16x8*)&yb[px * 64 + ((slot ^ (px & 7)) << 3)];
#pragma unroll
      for (int nt = 0; nt < 4; ++nt){
        const s16x8 bf = *(const s16x8*)(vt + (size_t)(nt * 16 + l15) * 64 + ks * 32 + lk * 8);
        tacc[nt] = MFMA16(af, bf, tacc[nt]);
      }
    }
  }
#pragma unroll
  for (int nt = 0; nt < 4; ++nt){
#pragma unroll
    for (int reg = 0; reg < 4; ++reg){
      const int pxo = wv * 16 + lk * 4 + reg;
      const int co = nt * 16 + l15;
      const int col = pxo + 1;
      const int elem = (66 + col) * 64 + (((co >> 3) ^ (col & 7)) << 3) + (co & 7);
      tb[(size_t)(p0 + pxo) * 64 + co] = f2bf(bf2f(xh[elem]) + tacc[nt][reg]);
    }
  }
}

// ---------------- conv1/conv2 (CIN=64): MFMA implicit GEMM, TROWS=4 ----------------
template<int COUT_FULL, bool RES, int MOUT>
__global__ __launch_bounds__(256)
void conv_mfma(const u16* __restrict__ in, const u16* __restrict__ wpk,
               const float* __restrict__ bias, const u16* __restrict__ res,
               void* __restrict__ out, const uint32* __restrict__ flag)
{
  if (MOUT >= 0){ if (*flag != (uint32)MOUT) return; }
  constexpr int TOT = 18;
  __shared__ __align__(16) u16 xh[6 * 66 * 64];
  __shared__ __align__(16) u16 Bb[3][2048];

  const int bx0 = blockIdx.x;
  const int bx  = (bx0 & 7) * 64 + (bx0 >> 3);   // XCD-chunked swizzle (512 wgs)
  const int img = bx >> 6;
  const int rem = bx & 63;
  const int h0  = (rem >> 1) * 4;
  const int w0  = (rem & 1) * 64;
  const int co0 = blockIdx.y * 64;
  const u16* __restrict__ wp = wpk + (size_t)blockIdx.y * TOT * 2048;

  auto stageB = [&](int it, int buf){
    const char* g = (const char*)(wp + (size_t)it * 2048) + threadIdx.x * 16;
    char* l = (char*)&Bb[buf][0] + threadIdx.x * 16;
    __builtin_amdgcn_global_load_lds((const __attribute__((address_space(1))) void*)g,
                                     (__attribute__((address_space(3))) void*)l, 16, 0, 0);
  };

  stage_tile<6, 64, 64>(in + (size_t)img * 16384 * 64, h0, w0, xh);
  stageB(0, 0);
  __syncthreads();

  const int lane = threadIdx.x & 63, wv = threadIdx.x >> 6;
  const int l15 = lane & 15, lk = lane >> 4;

  f32x4 acc[4][4];
#pragma unroll
  for (int nt = 0; nt < 4; ++nt){
    const float b = bias[co0 + nt * 16 + l15];
#pragma unroll
    for (int at = 0; at < 4; ++at) acc[at][nt] = (f32x4){b, b, b, b};
  }

#pragma unroll 1
  for (int it = 0; it < TOT; ++it){
    if (it + 1 < TOT){
      stageB(it + 1, (it + 1) % 3);
      asm volatile("s_waitcnt vmcnt(1)" ::: "memory");
    } else {
      asm volatile("s_waitcnt vmcnt(0)" ::: "memory");
    }
    __builtin_amdgcn_s_barrier();
    __builtin_amdgcn_sched_barrier(0);

    const int b = it % 3;
    const int tap = it >> 1, ks = it & 1;
    const int tr = tap / 3, tc = tap - tr * 3;
    const int slot = ks * 4 + lk;
    s16x8 av[4], bv[4];
#pragma unroll
    for (int at = 0; at < 4; ++at){
      const int col = at * 16 + l15 + tc;
      av[at] = *(const s16x8*)&xh[((wv + tr) * 66 + col) * 64 + ((slot ^ (col & 7)) << 3)];
    }
#pragma unroll
    for (int nt = 0; nt < 4; ++nt){
      const int co = nt * 16 + l15;
      bv[nt] = *(const s16x8*)&Bb[b][co * 32 + ((lk ^ ((co >> 1) & 3)) << 3)];
    }
#pragma unroll
    for (int at = 0; at < 4; ++at)
#pragma unroll
      for (int nt = 0; nt < 4; ++nt)
        acc[at][nt] = MFMA16(av[at], bv[nt], acc[at][nt]);
  }

#pragma unroll
  for (int at = 0; at < 4; ++at){
#pragma unroll
    for (int nt = 0; nt < 4; ++nt){
#pragma unroll
      for (int reg = 0; reg < 4; ++reg){
        float v = fmaxf(acc[at][nt][reg], 0.f);
        const int pxg = img * 16384 + (h0 + wv) * 128 + w0 + at * 16 + lk * 4 + reg;
        const int co  = co0 + nt * 16 + l15;
        const size_t oi = (size_t)pxg * COUT_FULL + co;
        if (RES) v += bf2f(res[oi]);
        if (MOUT == 0) ((float*)out)[oi] = v;
        else           ((u16*)out)[oi]   = f2bf(v);
      }
    }
  }
}

// ---------------- conv3 (CIN=128): TROWS=4 via two-phase ci-half staging ----------------
template<int MOUT>
__global__ __launch_bounds__(256)
void conv3_mfma(const u16* __restrict__ in, const u16* __restrict__ wpk,
                const float* __restrict__ bias, const u16* __restrict__ res,
                void* __restrict__ out, const uint32* __restrict__ flag)
{
  if (*flag != (uint32)MOUT) return;
  __shared__ __align__(16) u16 xh[6 * 66 * 64];
  __shared__ __align__(16) u16 Bb[3][2048];

  const int bx0 = blockIdx.x;
  const int bx  = (bx0 & 7) * 64 + (bx0 >> 3);   // XCD-chunked swizzle (512 wgs)
  const int img = bx >> 6;
  const int rem = bx & 63;
  const int h0  = (rem >> 1) * 4;
  const int w0  = (rem & 1) * 64;

  auto stageB = [&](int chunk, int buf){
    const char* g = (const char*)(wpk + (size_t)chunk * 2048) + threadIdx.x * 16;
    char* l = (char*)&Bb[buf][0] + threadIdx.x * 16;
    __builtin_amdgcn_global_load_lds((const __attribute__((address_space(1))) void*)g,
                                     (__attribute__((address_space(3))) void*)l, 16, 0, 0);
  };

  const int lane = threadIdx.x & 63, wv = threadIdx.x >> 6;
  const int l15 = lane & 15, lk = lane >> 4;

  f32x4 acc[4][4];
#pragma unroll
  for (int nt = 0; nt < 4; ++nt){
    const float b = bias[nt * 16 + l15];
#pragma unroll
    for (int at = 0; at < 4; ++at) acc[at][nt] = (f32x4){b, b, b, b};
  }

#pragma unroll 1
  for (int half = 0; half < 2; ++half){
    if (half) __syncthreads();
    stage_tile<6, 64, 128>(in + (size_t)img * 16384 * 128 + half * 64, h0, w0, xh);
    stageB(half * 2, 0);
    __syncthreads();

#pragma unroll 1
    for (int it = 0; it < 18; ++it){
      if (it + 1 < 18){
        const int tap1 = (it + 1) >> 1, ks1 = (it + 1) & 1;
        stageB(tap1 * 4 + half * 2 + ks1, (it + 1) % 3);
        asm volatile("s_waitcnt vmcnt(1)" ::: "memory");
      } else {
        asm volatile("s_waitcnt vmcnt(0)" ::: "memory");
      }
      __builtin_amdgcn_s_barrier();
      __builtin_amdgcn_sched_barrier(0);

      const int b = it % 3;
      const int tap = it >> 1, ks2 = it & 1;
      const int tr = tap / 3, tc = tap - tr * 3;
      const int slot = ks2 * 4 + lk;
      s16x8 av[4], bv[4];
#pragma unroll
      for (int at = 0; at < 4; ++at){
        const int col = at * 16 + l15 + tc;
        av[at] = *(const s16x8*)&xh[((wv + tr) * 66 + col) * 64 + ((slot ^ (col & 7)) << 3)];
      }
#pragma unroll
      for (int nt = 0; nt < 4; ++nt){
        const int co = nt * 16 + l15;
        bv[nt] = *(const s16x8*)&Bb[b][co * 32 + ((lk ^ ((co >> 1) & 3)) << 3)];
      }
#pragma unroll
      for (int at = 0; at < 4; ++at)
#pragma unroll
        for (int nt = 0; nt < 4; ++nt)
          acc[at][nt] = MFMA16(av[at], bv[nt], acc[at][nt]);
    }
  }

#pragma unroll
  for (int at = 0; at < 4; ++at){
#pragma unroll
    for (int nt = 0; nt < 4; ++nt){
#pragma unroll
      for (int reg = 0; reg < 4; ++reg){
        float v = fmaxf(acc[at][nt][reg], 0.f);
        const int pxg = img * 16384 + (h0 + wv) * 128 + w0 + at * 16 + lk * 4 + reg;
        const int co  = nt * 16 + l15;
        const size_t oi = (size_t)pxg * 64 + co;
        v += bf2f(res[oi]);
        if (MOUT == 0) ((float*)out)[oi] = v;
        else           ((u16*)out)[oi]   = f2bf(v);
      }
    }
  }
}

extern "C" void kernel_launch(void* const* d_in, const int* in_sizes, int n_in,
                              void* d_out, int out_size, void* d_ws, size_t ws_size,
                              hipStream_t stream)
{
  (void)in_sizes; (void)n_in; (void)out_size; (void)ws_size;

  char* ws = (char*)d_ws;
  float*  wblob = (float*)ws;                            // 196864 f32
  uint32* flag  = (uint32*)(ws + 983040);
  u16*    bb    = (u16*)(ws + (1u << 20));               // bf16 blob (196608)
  u16*    gt   = bb;                                     // [2][64][64] hi/lo
  u16*    vt   = bb + 8192;                              // [64][64]
  u16*    w1pk = bb + 12288;                             // 18 x 4KB chunks
  u16*    w2pk = bb + 49152;                             // 2 x 18 x 4KB
  u16*    w3pk = bb + 122880;                            // 36 x 4KB

  u16* xb = (u16*)(ws + (size_t)2097152);                // 16.78 MB (bf16 x, fp32 mode)
  u16* c2 = xb;                                          // reuses xb + tail (33.55 MB)
  u16* tb = (u16*)(ws + (size_t)35651584);               // 16.78 MB
  u16* c1 = (u16*)(ws + (size_t)52428800);               // 16.78 MB (ends 69.2 MB)

  detect_k<<<1, 64, 0, stream>>>((const uint32*)d_in[0], flag);

  cvtall_k<0><<<769, 256, 0, stream>>>(d_in[1], d_in[2], d_in[3], d_in[4], d_in[5],
                                       d_in[6], d_in[7], d_in[8], d_in[9], wblob, flag);
  cvtall_k<1><<<769, 256, 0, stream>>>(d_in[1], d_in[2], d_in[3], d_in[4], d_in[5],
                                       d_in[6], d_in[7], d_in[8], d_in[9], wblob, flag);

  xcvt_k<<<4096, 256, 0, stream>>>(d_in[0], xb, flag);   // fp32 mode only

  gcomp_k<<<16, 256, 0, stream>>>(wblob, gt);
  pack_k<<<736, 256, 0, stream>>>(wblob, bb);

  attn_mfma<<<2048, 256, 0, stream>>>((const u16*)d_in[0], xb, gt, vt, tb, flag);

  conv_mfma<64, false, -1><<<dim3(512, 1), 256, 0, stream>>>(
      tb, w1pk, wblob + 49152, nullptr, c1, flag);
  conv_mfma<128, false, -1><<<dim3(512, 2), 256, 0, stream>>>(
      c1, w2pk, wblob + 122944, nullptr, c2, flag);
  conv3_mfma<0><<<512, 256, 0, stream>>>(
      c2, w3pk, wblob + 196800, tb, d_out, flag);
  conv3_mfma<1><<<512, 256, 0, stream>>>(
      c2, w3pk, wblob + 196800, tb, d_out, flag);
}